// Round 4
// baseline (864.070 us; speedup 1.0000x reference)
//
#include <hip/hip_runtime.h>

typedef __attribute__((ext_vector_type(8))) short bf8_t;   // 8 bf16 = 4 VGPRs
typedef __attribute__((ext_vector_type(4))) float f4_t;

#define MFMA16(a, b, c) __builtin_amdgcn_mfma_f32_16x16x32_bf16((a), (b), (c), 0, 0, 0)

// Swizzled weight store (bf16 element offsets). Fragment-major: fragment block
// (nb,k) occupies 512 contiguous elems; lane (l15,quad) reads 16B at
// loff=(l15*4+quad)*8 -> one coalesced 1KB burst per wave B-load.
#define OFF_FC1 0          // 64x128   blocks [0,16)    t6 = nt*4+k
#define OFF_FC2 8192       // 64x192   blocks           t6 = nt*6+k
#define OFF_FC3 20480      // 32x64                     t6 = nt*2+k
#define OFF_AB1 22528      // 256x256                   t6 = nb*8+k
#define OFF_AB2 88064      // 256x256
#define W_CHUNKS 19200

// LDS row stride (bf16): [0:128)=x then z_hx[0:64)/z2[64:128), [128:384)=tanh(x)||tanh(m) then h1
#define ST 392

__device__ __forceinline__ unsigned short f2bf(float f) {
    unsigned int u = __builtin_bit_cast(unsigned int, f);
    u += 0x7FFFu + ((u >> 16) & 1u);               // round-to-nearest-even
    return (unsigned short)(u >> 16);
}

__device__ __forceinline__ float fast_tanh(float x) {
    float e = __builtin_amdgcn_exp2f(x * 2.885390081777927f);
    return 1.0f - 2.0f * __builtin_amdgcn_rcpf(e + 1.0f);
}

// fp32 weights -> bf16, fragment-major swizzle.
__global__ void convert_weights_kernel(const float* __restrict__ fc1w, const float* __restrict__ fc2w,
                                       const float* __restrict__ fc3w, const float* __restrict__ ab1w,
                                       const float* __restrict__ ab2w, unsigned short* __restrict__ wc) {
    int c = blockIdx.x * 256 + threadIdx.x;
    if (c >= W_CHUNKS) return;
    const float* p;
#define SWZ(SRC, LC, K32C, KC)                                                  \
    {                                                                           \
        int lc = (LC);                                                          \
        int quad = lc & 3, l15 = (lc >> 2) & 15, t6 = lc >> 6;                  \
        int k = t6 % (K32C), nb = t6 / (K32C);                                  \
        p = (SRC) + (size_t)(nb * 16 + l15) * (KC) + k * 32 + quad * 8;         \
    }
    if (c < 1024)       SWZ(fc1w, c,          4, 128)
    else if (c < 2560)  SWZ(fc2w, c - 1024,   6, 192)
    else if (c < 2816)  SWZ(fc3w, c - 2560,   2, 64)
    else if (c < 11008) SWZ(ab1w, c - 2816,   8, 256)
    else                SWZ(ab2w, c - 11008,  8, 256)
#undef SWZ
    float4 v0 = *(const float4*)p;
    float4 v1 = *(const float4*)(p + 4);
    ushort4 o0, o1;
    o0.x = f2bf(v0.x); o0.y = f2bf(v0.y); o0.z = f2bf(v0.z); o0.w = f2bf(v0.w);
    o1.x = f2bf(v1.x); o1.y = f2bf(v1.y); o1.z = f2bf(v1.z); o1.w = f2bf(v1.w);
    *(ushort4*)(wc + (size_t)c * 8)     = o0;
    *(ushort4*)(wc + (size_t)c * 8 + 4) = o1;
}

// Wave-specialized: 512 threads. Waves 0-3 = message branch (16 rows each),
// waves 4-7 = action branch (64-col N-chunk each). ab1/ab2 are ms-pass-split
// (acc 32 regs instead of 64) to hit the 85-reg budget of 6 waves/EU
// -> 3 blocks/CU (LDS 51200B allows 3). 4 barriers.
__global__ __launch_bounds__(512, 6)
void actor_fused_kernel(const float* __restrict__ x, const float* __restrict__ m,
                        const float* __restrict__ fc1_b, const float* __restrict__ fc2_b,
                        const float* __restrict__ fc3_b,
                        const float* __restrict__ ab_b1, const float* __restrict__ ab_b2,
                        const float* __restrict__ ab_w3, const float* __restrict__ ab_b3,
                        const unsigned short* __restrict__ wc,
                        float* __restrict__ out, int Brows)
{
    __shared__ __align__(16) unsigned short smem[64 * ST];
    __shared__ float pw[4][64];

    const int t    = threadIdx.x;
    const int wave = t >> 6;
    const int lane = t & 63;
    const int l15  = lane & 15;
    const int quad = lane >> 4;
    const int loff = (l15 * 4 + quad) * 8;     // lane offset within 512-elem fragment block
    const int r0   = blockIdx.x * 64;
    const int aw   = wave - 4;                 // action-wave index (valid for wave>=4)

    // ---------------- stage: x -> bf16 + tanh(x); m -> tanh(m) ----------------
    {
        const float* xp = x + (size_t)r0 * 128;
        const float* mp = m + (size_t)r0 * 128;
        #pragma unroll
        for (int i = 0; i < 4; i++) {
            int idx = t * 4 + i * 2048;        // coalesced float4 over [0,8192), 512 threads
            int row = idx >> 7, col = idx & 127;
            float4 v = *(const float4*)(xp + idx);
            float4 g = *(const float4*)(mp + idx);
            ushort4 raw, tx, tm;
            raw.x = f2bf(v.x); raw.y = f2bf(v.y); raw.z = f2bf(v.z); raw.w = f2bf(v.w);
            tx.x = f2bf(fast_tanh(v.x)); tx.y = f2bf(fast_tanh(v.y));
            tx.z = f2bf(fast_tanh(v.z)); tx.w = f2bf(fast_tanh(v.w));
            tm.x = f2bf(fast_tanh(g.x)); tm.y = f2bf(fast_tanh(g.y));
            tm.z = f2bf(fast_tanh(g.z)); tm.w = f2bf(fast_tanh(g.w));
            *(ushort4*)&smem[row * ST + col]       = raw;
            *(ushort4*)&smem[row * ST + 128 + col] = tx;
            *(ushort4*)&smem[row * ST + 256 + col] = tm;
        }
    }
    __syncthreads();   // S1: stage visible to all

    // Action-path state that must survive S2 (static live-set kept small:
    // nothing msg-side crosses S2 in registers).
    f4_t acc1[2][4];                 // ab1 pass-1 accumulator (rows 32..63)
    unsigned int h1p0[2][4][2];      // ab1 pass-0 h1, bf16-packed (rows 0..31)
    float ab1bia[4];

    if (wave < 4) {
        // ================= MESSAGE BRANCH pre-S2: fc1 + fc2 =================
        const int mrow = wave * 16;

        // ---- fc1: hx = x @ fc1_w^T + b ----
        f4_t hx[4] = {f4_t{0,0,0,0}, f4_t{0,0,0,0}, f4_t{0,0,0,0}, f4_t{0,0,0,0}};
        #pragma unroll
        for (int k = 0; k < 4; k++) {
            bf8_t a = *(const bf8_t*)&smem[(mrow + l15) * ST + k * 32 + quad * 8];
            #pragma unroll
            for (int nt = 0; nt < 4; nt++) {
                bf8_t b = *(const bf8_t*)(wc + OFF_FC1 + (nt * 4 + k) * 512 + loff);
                hx[nt] = MFMA16(a, b, hx[nt]);
            }
        }
        {
            float bia[4], ss[4] = {0, 0, 0, 0};
            #pragma unroll
            for (int nt = 0; nt < 4; nt++) bia[nt] = fc1_b[nt * 16 + l15];
            #pragma unroll
            for (int nt = 0; nt < 4; nt++)
                #pragma unroll
                for (int r = 0; r < 4; r++) { hx[nt][r] += bia[nt]; ss[r] += hx[nt][r] * hx[nt][r]; }
            #pragma unroll
            for (int off = 1; off < 16; off <<= 1)
                #pragma unroll
                for (int r = 0; r < 4; r++) ss[r] += __shfl_xor(ss[r], off, 64);
            float inv[4];
            #pragma unroll
            for (int r = 0; r < 4; r++) inv[r] = rsqrtf(fmaxf(ss[r], 1e-24f));
            // z_hx = tanh(l2norm(hx)) -> cols [0:64)  (own 16-row band only)
            #pragma unroll
            for (int nt = 0; nt < 4; nt++)
                #pragma unroll
                for (int r = 0; r < 4; r++)
                    smem[(mrow + quad * 4 + r) * ST + nt * 16 + l15] = f2bf(fast_tanh(hx[nt][r] * inv[r]));
        }
        // intra-wave LDS write->read ordering (own band only, no block barrier)
        asm volatile("s_waitcnt lgkmcnt(0)" ::: "memory");

        // ---- fc2: z2 = tanh([z_hx||tanh(m)] @ fc2_w^T + b)  K=192 ----
        f4_t z2[4] = {f4_t{0,0,0,0}, f4_t{0,0,0,0}, f4_t{0,0,0,0}, f4_t{0,0,0,0}};
        #pragma unroll
        for (int k = 0; k < 6; k++) {
            int acol = (k < 2) ? (k * 32 + quad * 8) : (192 + k * 32 + quad * 8); // z_hx | tanh(m)
            bf8_t a = *(const bf8_t*)&smem[(mrow + l15) * ST + acol];
            #pragma unroll
            for (int nt = 0; nt < 4; nt++) {
                bf8_t b = *(const bf8_t*)(wc + OFF_FC2 + (nt * 6 + k) * 512 + loff);
                z2[nt] = MFMA16(a, b, z2[nt]);
            }
        }
        {
            float bia[4];
            #pragma unroll
            for (int nt = 0; nt < 4; nt++) bia[nt] = fc2_b[nt * 16 + l15];
            #pragma unroll
            for (int nt = 0; nt < 4; nt++)
                #pragma unroll
                for (int r = 0; r < 4; r++)
                    smem[(mrow + quad * 4 + r) * ST + 64 + nt * 16 + l15] = f2bf(fast_tanh(z2[nt][r] + bia[nt]));
        }
        // z2 now in LDS; nothing msg-side stays in registers across S2.
    } else {
        // ================= ACTION BRANCH pre-S2: ab1 in two ms-passes =================
        #pragma unroll
        for (int nt = 0; nt < 4; nt++) ab1bia[nt] = ab_b1[aw * 64 + nt * 16 + l15];

        // ---- pass 0: rows 0..31; result immediately bias+relu'd to packed bf16 ----
        {
            f4_t accp[2][4];
            #pragma unroll
            for (int ms = 0; ms < 2; ms++)
                #pragma unroll
                for (int nt = 0; nt < 4; nt++) accp[ms][nt] = f4_t{0, 0, 0, 0};
            #pragma unroll
            for (int k = 0; k < 8; k++) {
                bf8_t a[2];
                #pragma unroll
                for (int ms = 0; ms < 2; ms++)
                    a[ms] = *(const bf8_t*)&smem[(ms * 16 + l15) * ST + 128 + k * 32 + quad * 8];
                #pragma unroll
                for (int nt = 0; nt < 4; nt++) {
                    bf8_t b = *(const bf8_t*)(wc + OFF_AB1 + ((aw * 4 + nt) * 8 + k) * 512 + loff);
                    #pragma unroll
                    for (int ms = 0; ms < 2; ms++) accp[ms][nt] = MFMA16(a[ms], b, accp[ms][nt]);
                }
            }
            #pragma unroll
            for (int ms = 0; ms < 2; ms++)
                #pragma unroll
                for (int nt = 0; nt < 4; nt++)
                    #pragma unroll
                    for (int j = 0; j < 2; j++) {
                        unsigned int lo = f2bf(fmaxf(accp[ms][nt][2 * j]     + ab1bia[nt], 0.0f));
                        unsigned int hi = f2bf(fmaxf(accp[ms][nt][2 * j + 1] + ab1bia[nt], 0.0f));
                        h1p0[ms][nt][j] = lo | (hi << 16);
                    }
        }
        // ---- pass 1: rows 32..63; acc carried across S2 ----
        #pragma unroll
        for (int ms = 0; ms < 2; ms++)
            #pragma unroll
            for (int nt = 0; nt < 4; nt++) acc1[ms][nt] = f4_t{0, 0, 0, 0};
        #pragma unroll
        for (int k = 0; k < 8; k++) {
            bf8_t a[2];
            #pragma unroll
            for (int ms = 0; ms < 2; ms++)
                a[ms] = *(const bf8_t*)&smem[((ms + 2) * 16 + l15) * ST + 128 + k * 32 + quad * 8];
            #pragma unroll
            for (int nt = 0; nt < 4; nt++) {
                bf8_t b = *(const bf8_t*)(wc + OFF_AB1 + ((aw * 4 + nt) * 8 + k) * 512 + loff);
                #pragma unroll
                for (int ms = 0; ms < 2; ms++) acc1[ms][nt] = MFMA16(a[ms], b, acc1[ms][nt]);
            }
        }
    }
    __syncthreads();   // S2: all tanh-region reads (msg fc2 + ab1 both passes) complete

    if (wave >= 4) {
        // h1 = relu(ab1 + b1) -> overwrite tanh region
        #pragma unroll
        for (int ms = 0; ms < 2; ms++)
            #pragma unroll
            for (int nt = 0; nt < 4; nt++)
                #pragma unroll
                for (int j = 0; j < 2; j++) {
                    unsigned int v = h1p0[ms][nt][j];
                    smem[(ms * 16 + quad * 4 + 2 * j)     * ST + 128 + aw * 64 + nt * 16 + l15] = (unsigned short)v;
                    smem[(ms * 16 + quad * 4 + 2 * j + 1) * ST + 128 + aw * 64 + nt * 16 + l15] = (unsigned short)(v >> 16);
                }
        #pragma unroll
        for (int ms = 0; ms < 2; ms++)
            #pragma unroll
            for (int nt = 0; nt < 4; nt++)
                #pragma unroll
                for (int r = 0; r < 4; r++)
                    smem[((ms + 2) * 16 + quad * 4 + r) * ST + 128 + aw * 64 + nt * 16 + l15] =
                        f2bf(fmaxf(acc1[ms][nt][r] + ab1bia[nt], 0.0f));
    }
    __syncthreads();   // S3: h1 visible; msg fc3 overlaps ab2 below

    if (wave < 4) {
        // ---- fc3: msg = l2norm(z2 @ fc3_w^T + b)  K=64, N=32 (overlaps ab2) ----
        const int mrow = wave * 16;
        f4_t mg[2] = {f4_t{0,0,0,0}, f4_t{0,0,0,0}};
        #pragma unroll
        for (int k = 0; k < 2; k++) {
            bf8_t a = *(const bf8_t*)&smem[(mrow + l15) * ST + 64 + k * 32 + quad * 8];
            #pragma unroll
            for (int nt = 0; nt < 2; nt++) {
                bf8_t b = *(const bf8_t*)(wc + OFF_FC3 + (nt * 2 + k) * 512 + loff);
                mg[nt] = MFMA16(a, b, mg[nt]);
            }
        }
        float bia[2], ss[4] = {0, 0, 0, 0};
        #pragma unroll
        for (int nt = 0; nt < 2; nt++) bia[nt] = fc3_b[nt * 16 + l15];
        #pragma unroll
        for (int nt = 0; nt < 2; nt++)
            #pragma unroll
            for (int r = 0; r < 4; r++) { mg[nt][r] += bia[nt]; ss[r] += mg[nt][r] * mg[nt][r]; }
        #pragma unroll
        for (int off = 1; off < 16; off <<= 1)
            #pragma unroll
            for (int r = 0; r < 4; r++) ss[r] += __shfl_xor(ss[r], off, 64);
        float inv[4];
        #pragma unroll
        for (int r = 0; r < 4; r++) inv[r] = rsqrtf(fmaxf(ss[r], 1e-24f));
        #pragma unroll
        for (int nt = 0; nt < 2; nt++)
            #pragma unroll
            for (int r = 0; r < 4; r++)
                out[(size_t)(r0 + mrow + quad * 4 + r) * 32 + nt * 16 + l15] = mg[nt][r] * inv[r];
    } else {
        // ---- ab2: h2 = relu(h1 @ w2^T + b2), fused ab3 dot; two ms-passes ----
        float ab2bia[4], w3v[4];
        #pragma unroll
        for (int nt = 0; nt < 4; nt++) {
            ab2bia[nt] = ab_b2[aw * 64 + nt * 16 + l15];
            w3v[nt]    = ab_w3[aw * 64 + nt * 16 + l15];
        }
        float p[4][4];
        #pragma unroll
        for (int pass = 0; pass < 2; pass++) {
            f4_t accp[2][4];
            #pragma unroll
            for (int ms = 0; ms < 2; ms++)
                #pragma unroll
                for (int nt = 0; nt < 4; nt++) accp[ms][nt] = f4_t{0, 0, 0, 0};
            #pragma unroll
            for (int k = 0; k < 8; k++) {
                bf8_t a[2];
                #pragma unroll
                for (int ms = 0; ms < 2; ms++)
                    a[ms] = *(const bf8_t*)&smem[((pass * 2 + ms) * 16 + l15) * ST + 128 + k * 32 + quad * 8];
                #pragma unroll
                for (int nt = 0; nt < 4; nt++) {
                    bf8_t b = *(const bf8_t*)(wc + OFF_AB2 + ((aw * 4 + nt) * 8 + k) * 512 + loff);
                    #pragma unroll
                    for (int ms = 0; ms < 2; ms++) accp[ms][nt] = MFMA16(a[ms], b, accp[ms][nt]);
                }
            }
            #pragma unroll
            for (int ms = 0; ms < 2; ms++)
                #pragma unroll
                for (int r = 0; r < 4; r++) {
                    float s = 0.0f;
                    #pragma unroll
                    for (int nt = 0; nt < 4; nt++) s += fmaxf(accp[ms][nt][r] + ab2bia[nt], 0.0f) * w3v[nt];
                    p[pass * 2 + ms][r] = s;
                }
        }
        #pragma unroll
        for (int off = 1; off < 16; off <<= 1)
            #pragma unroll
            for (int ms = 0; ms < 4; ms++)
                #pragma unroll
                for (int r = 0; r < 4; r++) p[ms][r] += __shfl_xor(p[ms][r], off, 64);
        if (l15 == 0) {
            #pragma unroll
            for (int ms = 0; ms < 4; ms++)
                #pragma unroll
                for (int r = 0; r < 4; r++) pw[aw][ms * 16 + quad * 4 + r] = p[ms][r];
        }
    }
    __syncthreads();   // S4: pw visible

    if (t < 64) {
        float a = pw[0][t] + pw[1][t] + pw[2][t] + pw[3][t] + ab_b3[0];
        out[(size_t)Brows * 32 + r0 + t] = fast_tanh(a);   // MAX_ACTION = 1
    }
}

extern "C" void kernel_launch(void* const* d_in, const int* in_sizes, int n_in,
                              void* d_out, int out_size, void* d_ws, size_t ws_size,
                              hipStream_t stream) {
    const float* x     = (const float*)d_in[0];
    const float* m     = (const float*)d_in[1];
    const float* fc1_w = (const float*)d_in[2];
    const float* fc1_b = (const float*)d_in[3];
    const float* fc2_w = (const float*)d_in[4];
    const float* fc2_b = (const float*)d_in[5];
    const float* fc3_w = (const float*)d_in[6];
    const float* fc3_b = (const float*)d_in[7];
    const float* ab_w1 = (const float*)d_in[8];
    const float* ab_b1 = (const float*)d_in[9];
    const float* ab_w2 = (const float*)d_in[10];
    const float* ab_b2 = (const float*)d_in[11];
    const float* ab_w3 = (const float*)d_in[12];
    const float* ab_b3 = (const float*)d_in[13];
    float* out = (float*)d_out;
    unsigned short* wc = (unsigned short*)d_ws;
    int Brows = in_sizes[0] / 128;   // 262144

    convert_weights_kernel<<<(W_CHUNKS + 255) / 256, 256, 0, stream>>>(fc1_w, fc2_w, fc3_w, ab_w1, ab_w2, wc);
    actor_fused_kernel<<<Brows / 64, 512, 0, stream>>>(x, m, fc1_b, fc2_b, fc3_b,
                                                       ab_b1, ab_b2, ab_w3, ab_b3, wc, out, Brows);
}

// Round 8
// 454.795 us; speedup vs baseline: 1.8999x; 1.8999x over previous
//
#include <hip/hip_runtime.h>

typedef __attribute__((ext_vector_type(8))) short bf8_t;   // 8 bf16 = 4 VGPRs
typedef __attribute__((ext_vector_type(4))) float f4_t;

#define MFMA16(a, b, c) __builtin_amdgcn_mfma_f32_16x16x32_bf16((a), (b), (c), 0, 0, 0)

// Swizzled weight store (bf16 element offsets). Fragment-major: fragment block
// (nb,k) occupies 512 contiguous elems; lane (l15,quad) reads 16B at
// loff=(l15*4+quad)*8 -> one coalesced 1KB burst per wave B-load.
#define OFF_FC1 0          // 64x128   blocks [0,16)    t6 = nt*4+k
#define OFF_FC2 8192       // 64x192   blocks           t6 = nt*6+k
#define OFF_FC3 20480      // 32x64                     t6 = nt*2+k
#define OFF_AB1 22528      // 256x256                   t6 = nb*8+k
#define OFF_AB2 88064      // 256x256
#define W_CHUNKS 19200

// LDS row stride (bf16): [0:128)=x then z_hx[0:64)/z2[64:128), [128:384)=tanh(x)||tanh(m) then h1
#define ST 392

__device__ __forceinline__ unsigned short f2bf(float f) {
    unsigned int u = __builtin_bit_cast(unsigned int, f);
    u += 0x7FFFu + ((u >> 16) & 1u);               // round-to-nearest-even
    return (unsigned short)(u >> 16);
}

__device__ __forceinline__ float fast_tanh(float x) {
    float e = __builtin_amdgcn_exp2f(x * 2.885390081777927f);
    return 1.0f - 2.0f * __builtin_amdgcn_rcpf(e + 1.0f);
}

// fp32 weights -> bf16, fragment-major swizzle.
__global__ void convert_weights_kernel(const float* __restrict__ fc1w, const float* __restrict__ fc2w,
                                       const float* __restrict__ fc3w, const float* __restrict__ ab1w,
                                       const float* __restrict__ ab2w, unsigned short* __restrict__ wc) {
    int c = blockIdx.x * 256 + threadIdx.x;
    if (c >= W_CHUNKS) return;
    const float* p;
#define SWZ(SRC, LC, K32C, KC)                                                  \
    {                                                                           \
        int lc = (LC);                                                          \
        int quad = lc & 3, l15 = (lc >> 2) & 15, t6 = lc >> 6;                  \
        int k = t6 % (K32C), nb = t6 / (K32C);                                  \
        p = (SRC) + (size_t)(nb * 16 + l15) * (KC) + k * 32 + quad * 8;         \
    }
    if (c < 1024)       SWZ(fc1w, c,          4, 128)
    else if (c < 2560)  SWZ(fc2w, c - 1024,   6, 192)
    else if (c < 2816)  SWZ(fc3w, c - 2560,   2, 64)
    else if (c < 11008) SWZ(ab1w, c - 2816,   8, 256)
    else                SWZ(ab2w, c - 11008,  8, 256)
#undef SWZ
    float4 v0 = *(const float4*)p;
    float4 v1 = *(const float4*)(p + 4);
    ushort4 o0, o1;
    o0.x = f2bf(v0.x); o0.y = f2bf(v0.y); o0.z = f2bf(v0.z); o0.w = f2bf(v0.w);
    o1.x = f2bf(v1.x); o1.y = f2bf(v1.y); o1.z = f2bf(v1.z); o1.w = f2bf(v1.w);
    *(ushort4*)(wc + (size_t)c * 8)     = o0;
    *(ushort4*)(wc + (size_t)c * 8 + 4) = o1;
}

// Wave-specialized: 512 threads. Waves 0-3 = message branch (16 rows each),
// waves 4-7 = action branch (64-col N-chunk each). Stage issues all 8 global
// loads as one clause (8 outstanding/thread) before any VALU. (512,4): the
// 64-float accumulator makes <128-reg budgets spill (round-4 evidence).
__global__ __launch_bounds__(512, 4)
void actor_fused_kernel(const float* __restrict__ x, const float* __restrict__ m,
                        const float* __restrict__ fc1_b, const float* __restrict__ fc2_b,
                        const float* __restrict__ fc3_b,
                        const float* __restrict__ ab_b1, const float* __restrict__ ab_b2,
                        const float* __restrict__ ab_w3, const float* __restrict__ ab_b3,
                        const unsigned short* __restrict__ wc,
                        float* __restrict__ out, int Brows)
{
    __shared__ __align__(16) unsigned short smem[64 * ST];
    __shared__ float pw[4][64];

    const int t    = threadIdx.x;
    const int wave = t >> 6;
    const int lane = t & 63;
    const int l15  = lane & 15;
    const int quad = lane >> 4;
    const int loff = (l15 * 4 + quad) * 8;     // lane offset within 512-elem fragment block
    const int r0   = blockIdx.x * 64;
    const int aw   = wave - 4;                 // action-wave index (valid for wave>=4)

    // ---------------- stage: x -> bf16 + tanh(x); m -> tanh(m) ----------------
    // Load clause first: 8 float4 in flight per thread, consumed in issue order
    // (in-order return => consuming vv[0] only waits for the oldest load).
    {
        const float* xp = x + (size_t)r0 * 128;
        const float* mp = m + (size_t)r0 * 128;
        float4 vv[4], gg[4];
        #pragma unroll
        for (int i = 0; i < 4; i++) {
            int idx = t * 4 + i * 2048;        // coalesced float4 over [0,8192), 512 threads
            vv[i] = *(const float4*)(xp + idx);
            gg[i] = *(const float4*)(mp + idx);
        }
        #pragma unroll
        for (int i = 0; i < 4; i++) {
            int idx = t * 4 + i * 2048;
            int row = idx >> 7, col = idx & 127;
            float4 v = vv[i];
            float4 g = gg[i];
            ushort4 raw, tx, tm;
            raw.x = f2bf(v.x); raw.y = f2bf(v.y); raw.z = f2bf(v.z); raw.w = f2bf(v.w);
            tx.x = f2bf(fast_tanh(v.x)); tx.y = f2bf(fast_tanh(v.y));
            tx.z = f2bf(fast_tanh(v.z)); tx.w = f2bf(fast_tanh(v.w));
            tm.x = f2bf(fast_tanh(g.x)); tm.y = f2bf(fast_tanh(g.y));
            tm.z = f2bf(fast_tanh(g.z)); tm.w = f2bf(fast_tanh(g.w));
            *(ushort4*)&smem[row * ST + col]       = raw;
            *(ushort4*)&smem[row * ST + 128 + col] = tx;
            *(ushort4*)&smem[row * ST + 256 + col] = tm;
        }
    }
    __syncthreads();   // S1: stage visible to all

    f4_t acc[4][4];    // action-branch ab1 accumulator; live across S2 (h1 write)

    if (wave < 4) {
        // ================= MESSAGE BRANCH pre-S2: fc1 + fc2 =================
        const int mrow = wave * 16;

        // ---- fc1: hx = x @ fc1_w^T + b ----
        f4_t hx[4] = {f4_t{0,0,0,0}, f4_t{0,0,0,0}, f4_t{0,0,0,0}, f4_t{0,0,0,0}};
        #pragma unroll
        for (int k = 0; k < 4; k++) {
            bf8_t a = *(const bf8_t*)&smem[(mrow + l15) * ST + k * 32 + quad * 8];
            #pragma unroll
            for (int nt = 0; nt < 4; nt++) {
                bf8_t b = *(const bf8_t*)(wc + OFF_FC1 + (nt * 4 + k) * 512 + loff);
                hx[nt] = MFMA16(a, b, hx[nt]);
            }
        }
        {
            float bia[4], ss[4] = {0, 0, 0, 0};
            #pragma unroll
            for (int nt = 0; nt < 4; nt++) bia[nt] = fc1_b[nt * 16 + l15];
            #pragma unroll
            for (int nt = 0; nt < 4; nt++)
                #pragma unroll
                for (int r = 0; r < 4; r++) { hx[nt][r] += bia[nt]; ss[r] += hx[nt][r] * hx[nt][r]; }
            #pragma unroll
            for (int off = 1; off < 16; off <<= 1)
                #pragma unroll
                for (int r = 0; r < 4; r++) ss[r] += __shfl_xor(ss[r], off, 64);
            float inv[4];
            #pragma unroll
            for (int r = 0; r < 4; r++) inv[r] = rsqrtf(fmaxf(ss[r], 1e-24f));
            // z_hx = tanh(l2norm(hx)) -> cols [0:64)  (own 16-row band only)
            #pragma unroll
            for (int nt = 0; nt < 4; nt++)
                #pragma unroll
                for (int r = 0; r < 4; r++)
                    smem[(mrow + quad * 4 + r) * ST + nt * 16 + l15] = f2bf(fast_tanh(hx[nt][r] * inv[r]));
        }
        // intra-wave LDS write->read ordering (own band only, no block barrier)
        asm volatile("s_waitcnt lgkmcnt(0)" ::: "memory");

        // ---- fc2: z2 = tanh([z_hx||tanh(m)] @ fc2_w^T + b)  K=192 ----
        f4_t z2[4] = {f4_t{0,0,0,0}, f4_t{0,0,0,0}, f4_t{0,0,0,0}, f4_t{0,0,0,0}};
        #pragma unroll
        for (int k = 0; k < 6; k++) {
            int acol = (k < 2) ? (k * 32 + quad * 8) : (192 + k * 32 + quad * 8); // z_hx | tanh(m)
            bf8_t a = *(const bf8_t*)&smem[(mrow + l15) * ST + acol];
            #pragma unroll
            for (int nt = 0; nt < 4; nt++) {
                bf8_t b = *(const bf8_t*)(wc + OFF_FC2 + (nt * 6 + k) * 512 + loff);
                z2[nt] = MFMA16(a, b, z2[nt]);
            }
        }
        {
            float bia[4];
            #pragma unroll
            for (int nt = 0; nt < 4; nt++) bia[nt] = fc2_b[nt * 16 + l15];
            #pragma unroll
            for (int nt = 0; nt < 4; nt++)
                #pragma unroll
                for (int r = 0; r < 4; r++)
                    smem[(mrow + quad * 4 + r) * ST + 64 + nt * 16 + l15] = f2bf(fast_tanh(z2[nt][r] + bia[nt]));
        }
        // z2 now in LDS; nothing msg-side stays in registers across S2.
    } else {
        // ================= ACTION BRANCH pre-S2: ab1 =================
        #pragma unroll
        for (int ms = 0; ms < 4; ms++)
            #pragma unroll
            for (int nt = 0; nt < 4; nt++) acc[ms][nt] = f4_t{0, 0, 0, 0};
        #pragma unroll
        for (int k = 0; k < 8; k++) {
            bf8_t a[4];
            #pragma unroll
            for (int ms = 0; ms < 4; ms++)
                a[ms] = *(const bf8_t*)&smem[(ms * 16 + l15) * ST + 128 + k * 32 + quad * 8];
            #pragma unroll
            for (int nt = 0; nt < 4; nt++) {
                bf8_t b = *(const bf8_t*)(wc + OFF_AB1 + ((aw * 4 + nt) * 8 + k) * 512 + loff);
                #pragma unroll
                for (int ms = 0; ms < 4; ms++) acc[ms][nt] = MFMA16(a[ms], b, acc[ms][nt]);
            }
        }
    }
    __syncthreads();   // S2: all tanh-region reads (msg fc2 + ab1) complete

    if (wave >= 4) {
        // h1 = relu(ab1 + b1) -> overwrite tanh region
        float bia[4];
        #pragma unroll
        for (int nt = 0; nt < 4; nt++) bia[nt] = ab_b1[aw * 64 + nt * 16 + l15];
        #pragma unroll
        for (int ms = 0; ms < 4; ms++)
            #pragma unroll
            for (int nt = 0; nt < 4; nt++)
                #pragma unroll
                for (int r = 0; r < 4; r++)
                    smem[(ms * 16 + quad * 4 + r) * ST + 128 + aw * 64 + nt * 16 + l15] =
                        f2bf(fmaxf(acc[ms][nt][r] + bia[nt], 0.0f));
    }
    __syncthreads();   // S3: h1 visible; msg fc3 overlaps ab2 below

    if (wave < 4) {
        // ---- fc3: msg = l2norm(z2 @ fc3_w^T + b)  K=64, N=32 (overlaps ab2) ----
        const int mrow = wave * 16;
        f4_t mg[2] = {f4_t{0,0,0,0}, f4_t{0,0,0,0}};
        #pragma unroll
        for (int k = 0; k < 2; k++) {
            bf8_t a = *(const bf8_t*)&smem[(mrow + l15) * ST + 64 + k * 32 + quad * 8];
            #pragma unroll
            for (int nt = 0; nt < 2; nt++) {
                bf8_t b = *(const bf8_t*)(wc + OFF_FC3 + (nt * 2 + k) * 512 + loff);
                mg[nt] = MFMA16(a, b, mg[nt]);
            }
        }
        float bia[2], ss[4] = {0, 0, 0, 0};
        #pragma unroll
        for (int nt = 0; nt < 2; nt++) bia[nt] = fc3_b[nt * 16 + l15];
        #pragma unroll
        for (int nt = 0; nt < 2; nt++)
            #pragma unroll
            for (int r = 0; r < 4; r++) { mg[nt][r] += bia[nt]; ss[r] += mg[nt][r] * mg[nt][r]; }
        #pragma unroll
        for (int off = 1; off < 16; off <<= 1)
            #pragma unroll
            for (int r = 0; r < 4; r++) ss[r] += __shfl_xor(ss[r], off, 64);
        float inv[4];
        #pragma unroll
        for (int r = 0; r < 4; r++) inv[r] = rsqrtf(fmaxf(ss[r], 1e-24f));
        #pragma unroll
        for (int nt = 0; nt < 2; nt++)
            #pragma unroll
            for (int r = 0; r < 4; r++)
                out[(size_t)(r0 + mrow + quad * 4 + r) * 32 + nt * 16 + l15] = mg[nt][r] * inv[r];
    } else {
        // ---- ab2: h2 = relu(h1 @ w2^T + b2), fused ab3 dot ----
        #pragma unroll
        for (int ms = 0; ms < 4; ms++)
            #pragma unroll
            for (int nt = 0; nt < 4; nt++) acc[ms][nt] = f4_t{0, 0, 0, 0};
        #pragma unroll
        for (int k = 0; k < 8; k++) {
            bf8_t a[4];
            #pragma unroll
            for (int ms = 0; ms < 4; ms++)
                a[ms] = *(const bf8_t*)&smem[(ms * 16 + l15) * ST + 128 + k * 32 + quad * 8];
            #pragma unroll
            for (int nt = 0; nt < 4; nt++) {
                bf8_t b = *(const bf8_t*)(wc + OFF_AB2 + ((aw * 4 + nt) * 8 + k) * 512 + loff);
                #pragma unroll
                for (int ms = 0; ms < 4; ms++) acc[ms][nt] = MFMA16(a[ms], b, acc[ms][nt]);
            }
        }
        {
            float bia[4], w3v[4];
            #pragma unroll
            for (int nt = 0; nt < 4; nt++) { bia[nt] = ab_b2[aw * 64 + nt * 16 + l15]; w3v[nt] = ab_w3[aw * 64 + nt * 16 + l15]; }
            float p[4][4];
            #pragma unroll
            for (int ms = 0; ms < 4; ms++)
                #pragma unroll
                for (int r = 0; r < 4; r++) {
                    float s = 0.0f;
                    #pragma unroll
                    for (int nt = 0; nt < 4; nt++) s += fmaxf(acc[ms][nt][r] + bia[nt], 0.0f) * w3v[nt];
                    p[ms][r] = s;
                }
            #pragma unroll
            for (int off = 1; off < 16; off <<= 1)
                #pragma unroll
                for (int ms = 0; ms < 4; ms++)
                    #pragma unroll
                    for (int r = 0; r < 4; r++) p[ms][r] += __shfl_xor(p[ms][r], off, 64);
            if (l15 == 0) {
                #pragma unroll
                for (int ms = 0; ms < 4; ms++)
                    #pragma unroll
                    for (int r = 0; r < 4; r++) pw[aw][ms * 16 + quad * 4 + r] = p[ms][r];
            }
        }
    }
    __syncthreads();   // S4: pw visible

    if (t < 64) {
        float a = pw[0][t] + pw[1][t] + pw[2][t] + pw[3][t] + ab_b3[0];
        out[(size_t)Brows * 32 + r0 + t] = fast_tanh(a);   // MAX_ACTION = 1
    }
}

extern "C" void kernel_launch(void* const* d_in, const int* in_sizes, int n_in,
                              void* d_out, int out_size, void* d_ws, size_t ws_size,
                              hipStream_t stream) {
    const float* x     = (const float*)d_in[0];
    const float* m     = (const float*)d_in[1];
    const float* fc1_w = (const float*)d_in[2];
    const float* fc1_b = (const float*)d_in[3];
    const float* fc2_w = (const float*)d_in[4];
    const float* fc2_b = (const float*)d_in[5];
    const float* fc3_w = (const float*)d_in[6];
    const float* fc3_b = (const float*)d_in[7];
    const float* ab_w1 = (const float*)d_in[8];
    const float* ab_b1 = (const float*)d_in[9];
    const float* ab_w2 = (const float*)d_in[10];
    const float* ab_b2 = (const float*)d_in[11];
    const float* ab_w3 = (const float*)d_in[12];
    const float* ab_b3 = (const float*)d_in[13];
    float* out = (float*)d_out;
    unsigned short* wc = (unsigned short*)d_ws;
    int Brows = in_sizes[0] / 128;   // 262144

    convert_weights_kernel<<<(W_CHUNKS + 255) / 256, 256, 0, stream>>>(fc1_w, fc2_w, fc3_w, ab_w1, ab_w2, wc);
    actor_fused_kernel<<<Brows / 64, 512, 0, stream>>>(x, m, fc1_b, fc2_b, fc3_b,
                                                       ab_b1, ab_b2, ab_w3, ab_b3, wc, out, Brows);
}

// Round 10
// 430.454 us; speedup vs baseline: 2.0073x; 1.0565x over previous
//
#include <hip/hip_runtime.h>

typedef __attribute__((ext_vector_type(8))) short bf8_t;   // 8 bf16 = 4 VGPRs
typedef __attribute__((ext_vector_type(4))) float f4_t;

#define MFMA16(a, b, c) __builtin_amdgcn_mfma_f32_16x16x32_bf16((a), (b), (c), 0, 0, 0)

// Swizzled weight store (bf16 element offsets). Fragment-major: fragment block
// (nb,k) occupies 512 contiguous elems; lane (l15,quad) reads 16B at
// loff=(l15*4+quad)*8 -> one coalesced 1KB burst per wave B-load.
#define OFF_FC1 0          // 64x128   blocks [0,16)    t6 = nt*4+k
#define OFF_FC2 8192       // 64x192   blocks           t6 = nt*6+k
#define OFF_FC3 20480      // 32x64                     t6 = nt*2+k
#define OFF_AB1 22528      // 256x256                   t6 = nb*8+k
#define OFF_AB2 88064      // 256x256
#define W_CHUNKS 19200

// LDS row stride (bf16): [0:128)=x then z_hx[0:64)/z2[64:128), [128:384)=tanh(x)||tanh(m) then h1
#define ST 392

__device__ __forceinline__ unsigned short f2bf(float f) {
    unsigned int u = __builtin_bit_cast(unsigned int, f);
    u += 0x7FFFu + ((u >> 16) & 1u);               // round-to-nearest-even
    return (unsigned short)(u >> 16);
}

__device__ __forceinline__ float fast_tanh(float x) {
    float e = __builtin_amdgcn_exp2f(x * 2.885390081777927f);
    return 1.0f - 2.0f * __builtin_amdgcn_rcpf(e + 1.0f);
}

// fp32 weights -> bf16, fragment-major swizzle.
__global__ void convert_weights_kernel(const float* __restrict__ fc1w, const float* __restrict__ fc2w,
                                       const float* __restrict__ fc3w, const float* __restrict__ ab1w,
                                       const float* __restrict__ ab2w, unsigned short* __restrict__ wc) {
    int c = blockIdx.x * 256 + threadIdx.x;
    if (c >= W_CHUNKS) return;
    const float* p;
#define SWZ(SRC, LC, K32C, KC)                                                  \
    {                                                                           \
        int lc = (LC);                                                          \
        int quad = lc & 3, l15 = (lc >> 2) & 15, t6 = lc >> 6;                  \
        int k = t6 % (K32C), nb = t6 / (K32C);                                  \
        p = (SRC) + (size_t)(nb * 16 + l15) * (KC) + k * 32 + quad * 8;         \
    }
    if (c < 1024)       SWZ(fc1w, c,          4, 128)
    else if (c < 2560)  SWZ(fc2w, c - 1024,   6, 192)
    else if (c < 2816)  SWZ(fc3w, c - 2560,   2, 64)
    else if (c < 11008) SWZ(ab1w, c - 2816,   8, 256)
    else                SWZ(ab2w, c - 11008,  8, 256)
#undef SWZ
    float4 v0 = *(const float4*)p;
    float4 v1 = *(const float4*)(p + 4);
    ushort4 o0, o1;
    o0.x = f2bf(v0.x); o0.y = f2bf(v0.y); o0.z = f2bf(v0.z); o0.w = f2bf(v0.w);
    o1.x = f2bf(v1.x); o1.y = f2bf(v1.y); o1.z = f2bf(v1.z); o1.w = f2bf(v1.w);
    *(ushort4*)(wc + (size_t)c * 8)     = o0;
    *(ushort4*)(wc + (size_t)c * 8 + 4) = o1;
}

// Wave-specialized: 512 threads. Waves 0-3 = message branch (16 rows each),
// waves 4-7 = action branch (64-col N-chunk each). All MFMA k-loops use an
// explicit 1-deep register double-buffer for the wc B-fragments, with each
// phase's k=0 fragments prefetched BEFORE the preceding barrier (L2 latency
// hides under the barrier wait). (512,4): 64-float acc makes <128-reg
// budgets spill (round-4 evidence).
__global__ __launch_bounds__(512, 4)
void actor_fused_kernel(const float* __restrict__ x, const float* __restrict__ m,
                        const float* __restrict__ fc1_b, const float* __restrict__ fc2_b,
                        const float* __restrict__ fc3_b,
                        const float* __restrict__ ab_b1, const float* __restrict__ ab_b2,
                        const float* __restrict__ ab_w3, const float* __restrict__ ab_b3,
                        const unsigned short* __restrict__ wc,
                        float* __restrict__ out, int Brows)
{
    __shared__ __align__(16) unsigned short smem[64 * ST];
    __shared__ float pw[4][64];

    const int t    = threadIdx.x;
    const int wave = t >> 6;
    const int lane = t & 63;
    const int l15  = lane & 15;
    const int quad = lane >> 4;
    const int loff = (l15 * 4 + quad) * 8;     // lane offset within 512-elem fragment block
    const int r0   = blockIdx.x * 64;
    const int aw   = wave - 4;                 // action-wave index (valid for wave>=4)

    // ---------------- stage: x -> bf16 + tanh(x); m -> tanh(m) ----------------
    {
        const float* xp = x + (size_t)r0 * 128;
        const float* mp = m + (size_t)r0 * 128;
        float4 vv[4], gg[4];
        #pragma unroll
        for (int i = 0; i < 4; i++) {
            int idx = t * 4 + i * 2048;        // coalesced float4 over [0,8192), 512 threads
            vv[i] = *(const float4*)(xp + idx);
            gg[i] = *(const float4*)(mp + idx);
        }
        #pragma unroll
        for (int i = 0; i < 4; i++) {
            int idx = t * 4 + i * 2048;
            int row = idx >> 7, col = idx & 127;
            float4 v = vv[i];
            float4 g = gg[i];
            ushort4 raw, tx, tm;
            raw.x = f2bf(v.x); raw.y = f2bf(v.y); raw.z = f2bf(v.z); raw.w = f2bf(v.w);
            tx.x = f2bf(fast_tanh(v.x)); tx.y = f2bf(fast_tanh(v.y));
            tx.z = f2bf(fast_tanh(v.z)); tx.w = f2bf(fast_tanh(v.w));
            tm.x = f2bf(fast_tanh(g.x)); tm.y = f2bf(fast_tanh(g.y));
            tm.z = f2bf(fast_tanh(g.z)); tm.w = f2bf(fast_tanh(g.w));
            *(ushort4*)&smem[row * ST + col]       = raw;
            *(ushort4*)&smem[row * ST + 128 + col] = tx;
            *(ushort4*)&smem[row * ST + 256 + col] = tm;
        }
    }

    // Prefetch k=0 B-fragments for the first post-S1 MFMA phase (fc1 / ab1):
    // pure-wc loads, independent of staging -> latency hides under S1 wait.
    bf8_t pf[4];
    if (wave < 4) {
        #pragma unroll
        for (int nt = 0; nt < 4; nt++)
            pf[nt] = *(const bf8_t*)(wc + OFF_FC1 + (nt * 4 + 0) * 512 + loff);
    } else {
        #pragma unroll
        for (int nt = 0; nt < 4; nt++)
            pf[nt] = *(const bf8_t*)(wc + OFF_AB1 + ((aw * 4 + nt) * 8 + 0) * 512 + loff);
    }
    __syncthreads();   // S1: stage visible to all

    f4_t acc[4][4];    // action-branch ab1 accumulator; live across S2 (h1 write)
    bf8_t pf2[4];      // prefetch for post-S3 phase (fc3 uses [0..3]; ab2 k=0)

    if (wave < 4) {
        // ================= MESSAGE BRANCH pre-S2: fc1 + fc2 =================
        const int mrow = wave * 16;

        // ---- fc1: hx = x @ fc1_w^T + b  (B double-buffered) ----
        f4_t hx[4] = {f4_t{0,0,0,0}, f4_t{0,0,0,0}, f4_t{0,0,0,0}, f4_t{0,0,0,0}};
        {
            bf8_t fb[2][4];
            #pragma unroll
            for (int nt = 0; nt < 4; nt++) fb[0][nt] = pf[nt];
            #pragma unroll
            for (int k = 0; k < 4; k++) {
                if (k < 3) {
                    #pragma unroll
                    for (int nt = 0; nt < 4; nt++)
                        fb[(k + 1) & 1][nt] = *(const bf8_t*)(wc + OFF_FC1 + (nt * 4 + k + 1) * 512 + loff);
                }
                bf8_t a = *(const bf8_t*)&smem[(mrow + l15) * ST + k * 32 + quad * 8];
                #pragma unroll
                for (int nt = 0; nt < 4; nt++)
                    hx[nt] = MFMA16(a, fb[k & 1][nt], hx[nt]);
            }
        }
        // fc2 k=0 prefetch: issues before the fc1 epilogue VALU, hides under it
        bf8_t fb2[2][4];
        #pragma unroll
        for (int nt = 0; nt < 4; nt++)
            fb2[0][nt] = *(const bf8_t*)(wc + OFF_FC2 + (nt * 6 + 0) * 512 + loff);
        {
            float bia[4], ss[4] = {0, 0, 0, 0};
            #pragma unroll
            for (int nt = 0; nt < 4; nt++) bia[nt] = fc1_b[nt * 16 + l15];
            #pragma unroll
            for (int nt = 0; nt < 4; nt++)
                #pragma unroll
                for (int r = 0; r < 4; r++) { hx[nt][r] += bia[nt]; ss[r] += hx[nt][r] * hx[nt][r]; }
            #pragma unroll
            for (int off = 1; off < 16; off <<= 1)
                #pragma unroll
                for (int r = 0; r < 4; r++) ss[r] += __shfl_xor(ss[r], off, 64);
            float inv[4];
            #pragma unroll
            for (int r = 0; r < 4; r++) inv[r] = rsqrtf(fmaxf(ss[r], 1e-24f));
            // z_hx = tanh(l2norm(hx)) -> cols [0:64)  (own 16-row band only)
            #pragma unroll
            for (int nt = 0; nt < 4; nt++)
                #pragma unroll
                for (int r = 0; r < 4; r++)
                    smem[(mrow + quad * 4 + r) * ST + nt * 16 + l15] = f2bf(fast_tanh(hx[nt][r] * inv[r]));
        }
        // intra-wave LDS write->read ordering (own band only, no block barrier)
        asm volatile("s_waitcnt lgkmcnt(0)" ::: "memory");

        // ---- fc2: z2 = tanh([z_hx||tanh(m)] @ fc2_w^T + b)  K=192 (B dbuf) ----
        f4_t z2[4] = {f4_t{0,0,0,0}, f4_t{0,0,0,0}, f4_t{0,0,0,0}, f4_t{0,0,0,0}};
        #pragma unroll
        for (int k = 0; k < 6; k++) {
            if (k < 5) {
                #pragma unroll
                for (int nt = 0; nt < 4; nt++)
                    fb2[(k + 1) & 1][nt] = *(const bf8_t*)(wc + OFF_FC2 + (nt * 6 + k + 1) * 512 + loff);
            }
            int acol = (k < 2) ? (k * 32 + quad * 8) : (192 + k * 32 + quad * 8); // z_hx | tanh(m)
            bf8_t a = *(const bf8_t*)&smem[(mrow + l15) * ST + acol];
            #pragma unroll
            for (int nt = 0; nt < 4; nt++)
                z2[nt] = MFMA16(a, fb2[k & 1][nt], z2[nt]);
        }
        {
            float bia[4];
            #pragma unroll
            for (int nt = 0; nt < 4; nt++) bia[nt] = fc2_b[nt * 16 + l15];
            #pragma unroll
            for (int nt = 0; nt < 4; nt++)
                #pragma unroll
                for (int r = 0; r < 4; r++)
                    smem[(mrow + quad * 4 + r) * ST + 64 + nt * 16 + l15] = f2bf(fast_tanh(z2[nt][r] + bia[nt]));
        }
        // z2 now in LDS; nothing msg-side stays in registers across S2 except pf2 (loaded below).
    } else {
        // ================= ACTION BRANCH pre-S2: ab1 (B double-buffered) =================
        #pragma unroll
        for (int ms = 0; ms < 4; ms++)
            #pragma unroll
            for (int nt = 0; nt < 4; nt++) acc[ms][nt] = f4_t{0, 0, 0, 0};
        bf8_t ab[2][4];
        #pragma unroll
        for (int nt = 0; nt < 4; nt++) ab[0][nt] = pf[nt];
        #pragma unroll
        for (int k = 0; k < 8; k++) {
            if (k < 7) {
                #pragma unroll
                for (int nt = 0; nt < 4; nt++)
                    ab[(k + 1) & 1][nt] = *(const bf8_t*)(wc + OFF_AB1 + ((aw * 4 + nt) * 8 + k + 1) * 512 + loff);
            }
            bf8_t a[4];
            #pragma unroll
            for (int ms = 0; ms < 4; ms++)
                a[ms] = *(const bf8_t*)&smem[(ms * 16 + l15) * ST + 128 + k * 32 + quad * 8];
            #pragma unroll
            for (int nt = 0; nt < 4; nt++)
                #pragma unroll
                for (int ms = 0; ms < 4; ms++) acc[ms][nt] = MFMA16(a[ms], ab[k & 1][nt], acc[ms][nt]);
        }
    }
    __syncthreads();   // S2: all tanh-region reads (msg fc2 + ab1) complete

    if (wave >= 4) {
        // h1 = relu(ab1 + b1) -> overwrite tanh region
        float bia[4];
        #pragma unroll
        for (int nt = 0; nt < 4; nt++) bia[nt] = ab_b1[aw * 64 + nt * 16 + l15];
        #pragma unroll
        for (int ms = 0; ms < 4; ms++)
            #pragma unroll
            for (int nt = 0; nt < 4; nt++)
                #pragma unroll
                for (int r = 0; r < 4; r++)
                    smem[(ms * 16 + quad * 4 + r) * ST + 128 + aw * 64 + nt * 16 + l15] =
                        f2bf(fmaxf(acc[ms][nt][r] + bia[nt], 0.0f));
        // ab2 k=0 prefetch: in flight across S3
        #pragma unroll
        for (int nt = 0; nt < 4; nt++)
            pf2[nt] = *(const bf8_t*)(wc + OFF_AB2 + ((aw * 4 + nt) * 8 + 0) * 512 + loff);
    } else {
        // fc3 B-fragments (all 4): in flight across S3
        #pragma unroll
        for (int k = 0; k < 2; k++)
            #pragma unroll
            for (int nt = 0; nt < 2; nt++)
                pf2[k * 2 + nt] = *(const bf8_t*)(wc + OFF_FC3 + (nt * 2 + k) * 512 + loff);
    }
    __syncthreads();   // S3: h1 visible; msg fc3 overlaps ab2 below

    if (wave < 4) {
        // ---- fc3: msg = l2norm(z2 @ fc3_w^T + b)  K=64, N=32 (overlaps ab2) ----
        const int mrow = wave * 16;
        f4_t mg[2] = {f4_t{0,0,0,0}, f4_t{0,0,0,0}};
        #pragma unroll
        for (int k = 0; k < 2; k++) {
            bf8_t a = *(const bf8_t*)&smem[(mrow + l15) * ST + 64 + k * 32 + quad * 8];
            #pragma unroll
            for (int nt = 0; nt < 2; nt++)
                mg[nt] = MFMA16(a, pf2[k * 2 + nt], mg[nt]);
        }
        float bia[2], ss[4] = {0, 0, 0, 0};
        #pragma unroll
        for (int nt = 0; nt < 2; nt++) bia[nt] = fc3_b[nt * 16 + l15];
        #pragma unroll
        for (int nt = 0; nt < 2; nt++)
            #pragma unroll
            for (int r = 0; r < 4; r++) { mg[nt][r] += bia[nt]; ss[r] += mg[nt][r] * mg[nt][r]; }
        #pragma unroll
        for (int off = 1; off < 16; off <<= 1)
            #pragma unroll
            for (int r = 0; r < 4; r++) ss[r] += __shfl_xor(ss[r], off, 64);
        float inv[4];
        #pragma unroll
        for (int r = 0; r < 4; r++) inv[r] = rsqrtf(fmaxf(ss[r], 1e-24f));
        #pragma unroll
        for (int nt = 0; nt < 2; nt++)
            #pragma unroll
            for (int r = 0; r < 4; r++)
                out[(size_t)(r0 + mrow + quad * 4 + r) * 32 + nt * 16 + l15] = mg[nt][r] * inv[r];
    } else {
        // ---- ab2: h2 = relu(h1 @ w2^T + b2), fused ab3 dot (B dbuf) ----
        #pragma unroll
        for (int ms = 0; ms < 4; ms++)
            #pragma unroll
            for (int nt = 0; nt < 4; nt++) acc[ms][nt] = f4_t{0, 0, 0, 0};
        bf8_t ab[2][4];
        #pragma unroll
        for (int nt = 0; nt < 4; nt++) ab[0][nt] = pf2[nt];
        #pragma unroll
        for (int k = 0; k < 8; k++) {
            if (k < 7) {
                #pragma unroll
                for (int nt = 0; nt < 4; nt++)
                    ab[(k + 1) & 1][nt] = *(const bf8_t*)(wc + OFF_AB2 + ((aw * 4 + nt) * 8 + k + 1) * 512 + loff);
            }
            bf8_t a[4];
            #pragma unroll
            for (int ms = 0; ms < 4; ms++)
                a[ms] = *(const bf8_t*)&smem[(ms * 16 + l15) * ST + 128 + k * 32 + quad * 8];
            #pragma unroll
            for (int nt = 0; nt < 4; nt++)
                #pragma unroll
                for (int ms = 0; ms < 4; ms++) acc[ms][nt] = MFMA16(a[ms], ab[k & 1][nt], acc[ms][nt]);
        }
        {
            float bia[4], w3v[4];
            #pragma unroll
            for (int nt = 0; nt < 4; nt++) { bia[nt] = ab_b2[aw * 64 + nt * 16 + l15]; w3v[nt] = ab_w3[aw * 64 + nt * 16 + l15]; }
            float p[4][4];
            #pragma unroll
            for (int ms = 0; ms < 4; ms++)
                #pragma unroll
                for (int r = 0; r < 4; r++) {
                    float s = 0.0f;
                    #pragma unroll
                    for (int nt = 0; nt < 4; nt++) s += fmaxf(acc[ms][nt][r] + bia[nt], 0.0f) * w3v[nt];
                    p[ms][r] = s;
                }
            #pragma unroll
            for (int off = 1; off < 16; off <<= 1)
                #pragma unroll
                for (int ms = 0; ms < 4; ms++)
                    #pragma unroll
                    for (int r = 0; r < 4; r++) p[ms][r] += __shfl_xor(p[ms][r], off, 64);
            if (l15 == 0) {
                #pragma unroll
                for (int ms = 0; ms < 4; ms++)
                    #pragma unroll
                    for (int r = 0; r < 4; r++) pw[aw][ms * 16 + quad * 4 + r] = p[ms][r];
            }
        }
    }
    __syncthreads();   // S4: pw visible

    if (t < 64) {
        float a = pw[0][t] + pw[1][t] + pw[2][t] + pw[3][t] + ab_b3[0];
        out[(size_t)Brows * 32 + r0 + t] = fast_tanh(a);   // MAX_ACTION = 1
    }
}

extern "C" void kernel_launch(void* const* d_in, const int* in_sizes, int n_in,
                              void* d_out, int out_size, void* d_ws, size_t ws_size,
                              hipStream_t stream) {
    const float* x     = (const float*)d_in[0];
    const float* m     = (const float*)d_in[1];
    const float* fc1_w = (const float*)d_in[2];
    const float* fc1_b = (const float*)d_in[3];
    const float* fc2_w = (const float*)d_in[4];
    const float* fc2_b = (const float*)d_in[5];
    const float* fc3_w = (const float*)d_in[6];
    const float* fc3_b = (const float*)d_in[7];
    const float* ab_w1 = (const float*)d_in[8];
    const float* ab_b1 = (const float*)d_in[9];
    const float* ab_w2 = (const float*)d_in[10];
    const float* ab_b2 = (const float*)d_in[11];
    const float* ab_w3 = (const float*)d_in[12];
    const float* ab_b3 = (const float*)d_in[13];
    float* out = (float*)d_out;
    unsigned short* wc = (unsigned short*)d_ws;
    int Brows = in_sizes[0] / 128;   // 262144

    convert_weights_kernel<<<(W_CHUNKS + 255) / 256, 256, 0, stream>>>(fc1_w, fc2_w, fc3_w, ab_w1, ab_w2, wc);
    actor_fused_kernel<<<Brows / 64, 512, 0, stream>>>(x, m, fc1_b, fc2_b, fc3_b,
                                                       ab_b1, ab_b2, ab_w3, ab_b3, wc, out, Brows);
}

// Round 11
// 425.549 us; speedup vs baseline: 2.0305x; 1.0115x over previous
//
#include <hip/hip_runtime.h>

typedef __attribute__((ext_vector_type(8))) short bf8_t;   // 8 bf16 = 4 VGPRs
typedef __attribute__((ext_vector_type(4))) float f4_t;

#define MFMA16(a, b, c) __builtin_amdgcn_mfma_f32_16x16x32_bf16((a), (b), (c), 0, 0, 0)

// Swizzled weight store (bf16 element offsets). Fragment-major: fragment block
// (nb,k) occupies 512 contiguous elems; lane (l15,quad) reads 16B at
// loff=(l15*4+quad)*8 -> one coalesced 1KB burst per wave B-load.
#define OFF_FC1 0          // 64x128   blocks [0,16)    t6 = nt*4+k
#define OFF_FC2 8192       // 64x192   blocks           t6 = nt*6+k
#define OFF_FC3 20480      // 32x64                     t6 = nt*2+k
#define OFF_AB1 22528      // 256x256                   t6 = nb*8+k
#define OFF_AB2 88064      // 256x256
#define W_CHUNKS 19200

// LDS row stride (bf16): [0:128)=x then z_hx[0:64)/z2[64:128), [128:384)=tanh(x)||tanh(m) then h1
#define ST 392

__device__ __forceinline__ unsigned short f2bf(float f) {
    unsigned int u = __builtin_bit_cast(unsigned int, f);
    u += 0x7FFFu + ((u >> 16) & 1u);               // round-to-nearest-even
    return (unsigned short)(u >> 16);
}

// 2x f32 -> packed bf16 (RNE), single HW instruction on gfx950.
__device__ __forceinline__ unsigned int cvt_pk_bf16(float lo, float hi) {
    unsigned int r;
    asm("v_cvt_pk_bf16_f32 %0, %1, %2" : "=v"(r) : "v"(lo), "v"(hi));
    return r;
}

__device__ __forceinline__ float fast_tanh(float x) {
    float e = __builtin_amdgcn_exp2f(x * 2.885390081777927f);
    return 1.0f - 2.0f * __builtin_amdgcn_rcpf(e + 1.0f);
}

// fp32 weights -> bf16, fragment-major swizzle.
__global__ void convert_weights_kernel(const float* __restrict__ fc1w, const float* __restrict__ fc2w,
                                       const float* __restrict__ fc3w, const float* __restrict__ ab1w,
                                       const float* __restrict__ ab2w, unsigned short* __restrict__ wc) {
    int c = blockIdx.x * 256 + threadIdx.x;
    if (c >= W_CHUNKS) return;
    const float* p;
#define SWZ(SRC, LC, K32C, KC)                                                  \
    {                                                                           \
        int lc = (LC);                                                          \
        int quad = lc & 3, l15 = (lc >> 2) & 15, t6 = lc >> 6;                  \
        int k = t6 % (K32C), nb = t6 / (K32C);                                  \
        p = (SRC) + (size_t)(nb * 16 + l15) * (KC) + k * 32 + quad * 8;         \
    }
    if (c < 1024)       SWZ(fc1w, c,          4, 128)
    else if (c < 2560)  SWZ(fc2w, c - 1024,   6, 192)
    else if (c < 2816)  SWZ(fc3w, c - 2560,   2, 64)
    else if (c < 11008) SWZ(ab1w, c - 2816,   8, 256)
    else                SWZ(ab2w, c - 11008,  8, 256)
#undef SWZ
    float4 v0 = *(const float4*)p;
    float4 v1 = *(const float4*)(p + 4);
    ushort4 o0, o1;
    o0.x = f2bf(v0.x); o0.y = f2bf(v0.y); o0.z = f2bf(v0.z); o0.w = f2bf(v0.w);
    o1.x = f2bf(v1.x); o1.y = f2bf(v1.y); o1.z = f2bf(v1.z); o1.w = f2bf(v1.w);
    *(ushort4*)(wc + (size_t)c * 8)     = o0;
    *(ushort4*)(wc + (size_t)c * 8 + 4) = o1;
}

// Wave-specialized: 512 threads. Waves 0-3 = message branch (16 rows each),
// waves 4-7 = action branch (64-col N-chunk each). All MFMA k-loops use an
// explicit 1-deep register double-buffer for the wc B-fragments, with each
// phase's k=0 fragments prefetched BEFORE the preceding barrier. All bf16
// conversions use v_cvt_pk_bf16_f32 (1 inst / 2 elems vs 4-inst manual RNE).
// (512,4): 64-float acc makes <128-reg budgets spill (round-4 evidence).
__global__ __launch_bounds__(512, 4)
void actor_fused_kernel(const float* __restrict__ x, const float* __restrict__ m,
                        const float* __restrict__ fc1_b, const float* __restrict__ fc2_b,
                        const float* __restrict__ fc3_b,
                        const float* __restrict__ ab_b1, const float* __restrict__ ab_b2,
                        const float* __restrict__ ab_w3, const float* __restrict__ ab_b3,
                        const unsigned short* __restrict__ wc,
                        float* __restrict__ out, int Brows)
{
    __shared__ __align__(16) unsigned short smem[64 * ST];
    __shared__ float pw[4][64];

    const int t    = threadIdx.x;
    const int wave = t >> 6;
    const int lane = t & 63;
    const int l15  = lane & 15;
    const int quad = lane >> 4;
    const int loff = (l15 * 4 + quad) * 8;     // lane offset within 512-elem fragment block
    const int r0   = blockIdx.x * 64;
    const int aw   = wave - 4;                 // action-wave index (valid for wave>=4)

    // ---------------- stage: x -> bf16 + tanh(x); m -> tanh(m) ----------------
    {
        const float* xp = x + (size_t)r0 * 128;
        const float* mp = m + (size_t)r0 * 128;
        float4 vv[4], gg[4];
        #pragma unroll
        for (int i = 0; i < 4; i++) {
            int idx = t * 4 + i * 2048;        // coalesced float4 over [0,8192), 512 threads
            vv[i] = *(const float4*)(xp + idx);
            gg[i] = *(const float4*)(mp + idx);
        }
        #pragma unroll
        for (int i = 0; i < 4; i++) {
            int idx = t * 4 + i * 2048;
            int row = idx >> 7, col = idx & 127;   // col % 4 == 0 -> 8B-aligned stores
            float4 v = vv[i];
            float4 g = gg[i];
            uint2 raw, tx, tm;
            raw.x = cvt_pk_bf16(v.x, v.y);
            raw.y = cvt_pk_bf16(v.z, v.w);
            tx.x  = cvt_pk_bf16(fast_tanh(v.x), fast_tanh(v.y));
            tx.y  = cvt_pk_bf16(fast_tanh(v.z), fast_tanh(v.w));
            tm.x  = cvt_pk_bf16(fast_tanh(g.x), fast_tanh(g.y));
            tm.y  = cvt_pk_bf16(fast_tanh(g.z), fast_tanh(g.w));
            *(uint2*)&smem[row * ST + col]       = raw;
            *(uint2*)&smem[row * ST + 128 + col] = tx;
            *(uint2*)&smem[row * ST + 256 + col] = tm;
        }
    }

    // Prefetch k=0 B-fragments for the first post-S1 MFMA phase (fc1 / ab1):
    // pure-wc loads, independent of staging -> latency hides under S1 wait.
    bf8_t pf[4];
    if (wave < 4) {
        #pragma unroll
        for (int nt = 0; nt < 4; nt++)
            pf[nt] = *(const bf8_t*)(wc + OFF_FC1 + (nt * 4 + 0) * 512 + loff);
    } else {
        #pragma unroll
        for (int nt = 0; nt < 4; nt++)
            pf[nt] = *(const bf8_t*)(wc + OFF_AB1 + ((aw * 4 + nt) * 8 + 0) * 512 + loff);
    }
    __syncthreads();   // S1: stage visible to all

    f4_t acc[4][4];    // action-branch ab1 accumulator; live across S2 (h1 write)
    bf8_t pf2[4];      // prefetch for post-S3 phase (fc3 uses [0..3]; ab2 k=0)

    if (wave < 4) {
        // ================= MESSAGE BRANCH pre-S2: fc1 + fc2 =================
        const int mrow = wave * 16;

        // ---- fc1: hx = x @ fc1_w^T + b  (B double-buffered) ----
        f4_t hx[4] = {f4_t{0,0,0,0}, f4_t{0,0,0,0}, f4_t{0,0,0,0}, f4_t{0,0,0,0}};
        {
            bf8_t fb[2][4];
            #pragma unroll
            for (int nt = 0; nt < 4; nt++) fb[0][nt] = pf[nt];
            #pragma unroll
            for (int k = 0; k < 4; k++) {
                if (k < 3) {
                    #pragma unroll
                    for (int nt = 0; nt < 4; nt++)
                        fb[(k + 1) & 1][nt] = *(const bf8_t*)(wc + OFF_FC1 + (nt * 4 + k + 1) * 512 + loff);
                }
                bf8_t a = *(const bf8_t*)&smem[(mrow + l15) * ST + k * 32 + quad * 8];
                #pragma unroll
                for (int nt = 0; nt < 4; nt++)
                    hx[nt] = MFMA16(a, fb[k & 1][nt], hx[nt]);
            }
        }
        // fc2 k=0 prefetch: issues before the fc1 epilogue VALU, hides under it
        bf8_t fb2[2][4];
        #pragma unroll
        for (int nt = 0; nt < 4; nt++)
            fb2[0][nt] = *(const bf8_t*)(wc + OFF_FC2 + (nt * 6 + 0) * 512 + loff);
        {
            float bia[4], ss[4] = {0, 0, 0, 0};
            #pragma unroll
            for (int nt = 0; nt < 4; nt++) bia[nt] = fc1_b[nt * 16 + l15];
            #pragma unroll
            for (int nt = 0; nt < 4; nt++)
                #pragma unroll
                for (int r = 0; r < 4; r++) { hx[nt][r] += bia[nt]; ss[r] += hx[nt][r] * hx[nt][r]; }
            #pragma unroll
            for (int off = 1; off < 16; off <<= 1)
                #pragma unroll
                for (int r = 0; r < 4; r++) ss[r] += __shfl_xor(ss[r], off, 64);
            float inv[4];
            #pragma unroll
            for (int r = 0; r < 4; r++) inv[r] = rsqrtf(fmaxf(ss[r], 1e-24f));
            // z_hx = tanh(l2norm(hx)) -> cols [0:64)  (own 16-row band only)
            #pragma unroll
            for (int nt = 0; nt < 4; nt++) {
                unsigned int p01 = cvt_pk_bf16(fast_tanh(hx[nt][0] * inv[0]), fast_tanh(hx[nt][1] * inv[1]));
                unsigned int p23 = cvt_pk_bf16(fast_tanh(hx[nt][2] * inv[2]), fast_tanh(hx[nt][3] * inv[3]));
                smem[(mrow + quad * 4 + 0) * ST + nt * 16 + l15] = (unsigned short)p01;
                smem[(mrow + quad * 4 + 1) * ST + nt * 16 + l15] = (unsigned short)(p01 >> 16);
                smem[(mrow + quad * 4 + 2) * ST + nt * 16 + l15] = (unsigned short)p23;
                smem[(mrow + quad * 4 + 3) * ST + nt * 16 + l15] = (unsigned short)(p23 >> 16);
            }
        }
        // intra-wave LDS write->read ordering (own band only, no block barrier)
        asm volatile("s_waitcnt lgkmcnt(0)" ::: "memory");

        // ---- fc2: z2 = tanh([z_hx||tanh(m)] @ fc2_w^T + b)  K=192 (B dbuf) ----
        f4_t z2[4] = {f4_t{0,0,0,0}, f4_t{0,0,0,0}, f4_t{0,0,0,0}, f4_t{0,0,0,0}};
        #pragma unroll
        for (int k = 0; k < 6; k++) {
            if (k < 5) {
                #pragma unroll
                for (int nt = 0; nt < 4; nt++)
                    fb2[(k + 1) & 1][nt] = *(const bf8_t*)(wc + OFF_FC2 + (nt * 6 + k + 1) * 512 + loff);
            }
            int acol = (k < 2) ? (k * 32 + quad * 8) : (192 + k * 32 + quad * 8); // z_hx | tanh(m)
            bf8_t a = *(const bf8_t*)&smem[(mrow + l15) * ST + acol];
            #pragma unroll
            for (int nt = 0; nt < 4; nt++)
                z2[nt] = MFMA16(a, fb2[k & 1][nt], z2[nt]);
        }
        {
            float bia[4];
            #pragma unroll
            for (int nt = 0; nt < 4; nt++) bia[nt] = fc2_b[nt * 16 + l15];
            #pragma unroll
            for (int nt = 0; nt < 4; nt++) {
                unsigned int p01 = cvt_pk_bf16(fast_tanh(z2[nt][0] + bia[nt]), fast_tanh(z2[nt][1] + bia[nt]));
                unsigned int p23 = cvt_pk_bf16(fast_tanh(z2[nt][2] + bia[nt]), fast_tanh(z2[nt][3] + bia[nt]));
                smem[(mrow + quad * 4 + 0) * ST + 64 + nt * 16 + l15] = (unsigned short)p01;
                smem[(mrow + quad * 4 + 1) * ST + 64 + nt * 16 + l15] = (unsigned short)(p01 >> 16);
                smem[(mrow + quad * 4 + 2) * ST + 64 + nt * 16 + l15] = (unsigned short)p23;
                smem[(mrow + quad * 4 + 3) * ST + 64 + nt * 16 + l15] = (unsigned short)(p23 >> 16);
            }
        }
        // z2 now in LDS; nothing msg-side stays in registers across S2 except pf2 (loaded below).
    } else {
        // ================= ACTION BRANCH pre-S2: ab1 (B double-buffered) =================
        #pragma unroll
        for (int ms = 0; ms < 4; ms++)
            #pragma unroll
            for (int nt = 0; nt < 4; nt++) acc[ms][nt] = f4_t{0, 0, 0, 0};
        bf8_t ab[2][4];
        #pragma unroll
        for (int nt = 0; nt < 4; nt++) ab[0][nt] = pf[nt];
        #pragma unroll
        for (int k = 0; k < 8; k++) {
            if (k < 7) {
                #pragma unroll
                for (int nt = 0; nt < 4; nt++)
                    ab[(k + 1) & 1][nt] = *(const bf8_t*)(wc + OFF_AB1 + ((aw * 4 + nt) * 8 + k + 1) * 512 + loff);
            }
            bf8_t a[4];
            #pragma unroll
            for (int ms = 0; ms < 4; ms++)
                a[ms] = *(const bf8_t*)&smem[(ms * 16 + l15) * ST + 128 + k * 32 + quad * 8];
            #pragma unroll
            for (int nt = 0; nt < 4; nt++)
                #pragma unroll
                for (int ms = 0; ms < 4; ms++) acc[ms][nt] = MFMA16(a[ms], ab[k & 1][nt], acc[ms][nt]);
        }
    }
    __syncthreads();   // S2: all tanh-region reads (msg fc2 + ab1) complete

    if (wave >= 4) {
        // h1 = relu(ab1 + b1) -> overwrite tanh region
        float bia[4];
        #pragma unroll
        for (int nt = 0; nt < 4; nt++) bia[nt] = ab_b1[aw * 64 + nt * 16 + l15];
        #pragma unroll
        for (int ms = 0; ms < 4; ms++)
            #pragma unroll
            for (int nt = 0; nt < 4; nt++) {
                unsigned int p01 = cvt_pk_bf16(fmaxf(acc[ms][nt][0] + bia[nt], 0.0f),
                                               fmaxf(acc[ms][nt][1] + bia[nt], 0.0f));
                unsigned int p23 = cvt_pk_bf16(fmaxf(acc[ms][nt][2] + bia[nt], 0.0f),
                                               fmaxf(acc[ms][nt][3] + bia[nt], 0.0f));
                smem[(ms * 16 + quad * 4 + 0) * ST + 128 + aw * 64 + nt * 16 + l15] = (unsigned short)p01;
                smem[(ms * 16 + quad * 4 + 1) * ST + 128 + aw * 64 + nt * 16 + l15] = (unsigned short)(p01 >> 16);
                smem[(ms * 16 + quad * 4 + 2) * ST + 128 + aw * 64 + nt * 16 + l15] = (unsigned short)p23;
                smem[(ms * 16 + quad * 4 + 3) * ST + 128 + aw * 64 + nt * 16 + l15] = (unsigned short)(p23 >> 16);
            }
        // ab2 k=0 prefetch: in flight across S3
        #pragma unroll
        for (int nt = 0; nt < 4; nt++)
            pf2[nt] = *(const bf8_t*)(wc + OFF_AB2 + ((aw * 4 + nt) * 8 + 0) * 512 + loff);
    } else {
        // fc3 B-fragments (all 4): in flight across S3
        #pragma unroll
        for (int k = 0; k < 2; k++)
            #pragma unroll
            for (int nt = 0; nt < 2; nt++)
                pf2[k * 2 + nt] = *(const bf8_t*)(wc + OFF_FC3 + (nt * 2 + k) * 512 + loff);
    }
    __syncthreads();   // S3: h1 visible; msg fc3 overlaps ab2 below

    if (wave < 4) {
        // ---- fc3: msg = l2norm(z2 @ fc3_w^T + b)  K=64, N=32 (overlaps ab2) ----
        const int mrow = wave * 16;
        f4_t mg[2] = {f4_t{0,0,0,0}, f4_t{0,0,0,0}};
        #pragma unroll
        for (int k = 0; k < 2; k++) {
            bf8_t a = *(const bf8_t*)&smem[(mrow + l15) * ST + 64 + k * 32 + quad * 8];
            #pragma unroll
            for (int nt = 0; nt < 2; nt++)
                mg[nt] = MFMA16(a, pf2[k * 2 + nt], mg[nt]);
        }
        float bia[2], ss[4] = {0, 0, 0, 0};
        #pragma unroll
        for (int nt = 0; nt < 2; nt++) bia[nt] = fc3_b[nt * 16 + l15];
        #pragma unroll
        for (int nt = 0; nt < 2; nt++)
            #pragma unroll
            for (int r = 0; r < 4; r++) { mg[nt][r] += bia[nt]; ss[r] += mg[nt][r] * mg[nt][r]; }
        #pragma unroll
        for (int off = 1; off < 16; off <<= 1)
            #pragma unroll
            for (int r = 0; r < 4; r++) ss[r] += __shfl_xor(ss[r], off, 64);
        float inv[4];
        #pragma unroll
        for (int r = 0; r < 4; r++) inv[r] = rsqrtf(fmaxf(ss[r], 1e-24f));
        #pragma unroll
        for (int nt = 0; nt < 2; nt++)
            #pragma unroll
            for (int r = 0; r < 4; r++)
                out[(size_t)(r0 + mrow + quad * 4 + r) * 32 + nt * 16 + l15] = mg[nt][r] * inv[r];
    } else {
        // ---- ab2: h2 = relu(h1 @ w2^T + b2), fused ab3 dot (B dbuf) ----
        #pragma unroll
        for (int ms = 0; ms < 4; ms++)
            #pragma unroll
            for (int nt = 0; nt < 4; nt++) acc[ms][nt] = f4_t{0, 0, 0, 0};
        bf8_t ab[2][4];
        #pragma unroll
        for (int nt = 0; nt < 4; nt++) ab[0][nt] = pf2[nt];
        #pragma unroll
        for (int k = 0; k < 8; k++) {
            if (k < 7) {
                #pragma unroll
                for (int nt = 0; nt < 4; nt++)
                    ab[(k + 1) & 1][nt] = *(const bf8_t*)(wc + OFF_AB2 + ((aw * 4 + nt) * 8 + k + 1) * 512 + loff);
            }
            bf8_t a[4];
            #pragma unroll
            for (int ms = 0; ms < 4; ms++)
                a[ms] = *(const bf8_t*)&smem[(ms * 16 + l15) * ST + 128 + k * 32 + quad * 8];
            #pragma unroll
            for (int nt = 0; nt < 4; nt++)
                #pragma unroll
                for (int ms = 0; ms < 4; ms++) acc[ms][nt] = MFMA16(a[ms], ab[k & 1][nt], acc[ms][nt]);
        }
        {
            float bia[4], w3v[4];
            #pragma unroll
            for (int nt = 0; nt < 4; nt++) { bia[nt] = ab_b2[aw * 64 + nt * 16 + l15]; w3v[nt] = ab_w3[aw * 64 + nt * 16 + l15]; }
            float p[4][4];
            #pragma unroll
            for (int ms = 0; ms < 4; ms++)
                #pragma unroll
                for (int r = 0; r < 4; r++) {
                    float s = 0.0f;
                    #pragma unroll
                    for (int nt = 0; nt < 4; nt++) s += fmaxf(acc[ms][nt][r] + bia[nt], 0.0f) * w3v[nt];
                    p[ms][r] = s;
                }
            #pragma unroll
            for (int off = 1; off < 16; off <<= 1)
                #pragma unroll
                for (int ms = 0; ms < 4; ms++)
                    #pragma unroll
                    for (int r = 0; r < 4; r++) p[ms][r] += __shfl_xor(p[ms][r], off, 64);
            if (l15 == 0) {
                #pragma unroll
                for (int ms = 0; ms < 4; ms++)
                    #pragma unroll
                    for (int r = 0; r < 4; r++) pw[aw][ms * 16 + quad * 4 + r] = p[ms][r];
            }
        }
    }
    __syncthreads();   // S4: pw visible

    if (t < 64) {
        float a = pw[0][t] + pw[1][t] + pw[2][t] + pw[3][t] + ab_b3[0];
        out[(size_t)Brows * 32 + r0 + t] = fast_tanh(a);   // MAX_ACTION = 1
    }
}

extern "C" void kernel_launch(void* const* d_in, const int* in_sizes, int n_in,
                              void* d_out, int out_size, void* d_ws, size_t ws_size,
                              hipStream_t stream) {
    const float* x     = (const float*)d_in[0];
    const float* m     = (const float*)d_in[1];
    const float* fc1_w = (const float*)d_in[2];
    const float* fc1_b = (const float*)d_in[3];
    const float* fc2_w = (const float*)d_in[4];
    const float* fc2_b = (const float*)d_in[5];
    const float* fc3_w = (const float*)d_in[6];
    const float* fc3_b = (const float*)d_in[7];
    const float* ab_w1 = (const float*)d_in[8];
    const float* ab_b1 = (const float*)d_in[9];
    const float* ab_w2 = (const float*)d_in[10];
    const float* ab_b2 = (const float*)d_in[11];
    const float* ab_w3 = (const float*)d_in[12];
    const float* ab_b3 = (const float*)d_in[13];
    float* out = (float*)d_out;
    unsigned short* wc = (unsigned short*)d_ws;
    int Brows = in_sizes[0] / 128;   // 262144

    convert_weights_kernel<<<(W_CHUNKS + 255) / 256, 256, 0, stream>>>(fc1_w, fc2_w, fc3_w, ab_w1, ab_w2, wc);
    actor_fused_kernel<<<Brows / 64, 512, 0, stream>>>(x, m, fc1_b, fc2_b, fc3_b,
                                                       ab_b1, ab_b2, ab_w3, ab_b3, wc, out, Brows);
}

// Round 12
// 391.952 us; speedup vs baseline: 2.2045x; 1.0857x over previous
//
#include <hip/hip_runtime.h>

typedef __attribute__((ext_vector_type(8))) short bf8_t;   // 8 bf16 = 4 VGPRs
typedef __attribute__((ext_vector_type(4))) float f4_t;

#define MFMA16(a, b, c) __builtin_amdgcn_mfma_f32_16x16x32_bf16((a), (b), (c), 0, 0, 0)

// Swizzled weight store (bf16 element offsets). Fragment-major: fragment block
// (nb,k) occupies 512 contiguous elems; lane (l15,quad) reads 16B at
// loff=(l15*4+quad)*8 -> one coalesced 1KB burst per wave B-load.
#define OFF_FC1 0          // 64x128   blocks [0,16)    t6 = nt*4+k
#define OFF_FC2 8192       // 64x192   blocks           t6 = nt*6+k
#define OFF_FC3 20480      // 32x64                     t6 = nt*2+k
#define OFF_AB1 22528      // 256x256                   t6 = nb*8+k
#define OFF_AB2 88064      // 256x256
#define W_CHUNKS 19200

// LDS row stride (bf16): [0:128)=x then z_hx[0:64)/z2[64:128), [128:384)=tanh(x)||tanh(m) then h1
#define ST 392

__device__ __forceinline__ unsigned short f2bf(float f) {
    unsigned int u = __builtin_bit_cast(unsigned int, f);
    u += 0x7FFFu + ((u >> 16) & 1u);               // round-to-nearest-even
    return (unsigned short)(u >> 16);
}

// 2x f32 -> packed bf16 (RNE), single HW instruction on gfx950.
__device__ __forceinline__ unsigned int cvt_pk_bf16(float lo, float hi) {
    unsigned int r;
    asm("v_cvt_pk_bf16_f32 %0, %1, %2" : "=v"(r) : "v"(lo), "v"(hi));
    return r;
}

__device__ __forceinline__ float fast_tanh(float x) {
    float e = __builtin_amdgcn_exp2f(x * 2.885390081777927f);
    return 1.0f - 2.0f * __builtin_amdgcn_rcpf(e + 1.0f);
}

// fp32 weights -> bf16, fragment-major swizzle.
__global__ void convert_weights_kernel(const float* __restrict__ fc1w, const float* __restrict__ fc2w,
                                       const float* __restrict__ fc3w, const float* __restrict__ ab1w,
                                       const float* __restrict__ ab2w, unsigned short* __restrict__ wc) {
    int c = blockIdx.x * 256 + threadIdx.x;
    if (c >= W_CHUNKS) return;
    const float* p;
#define SWZ(SRC, LC, K32C, KC)                                                  \
    {                                                                           \
        int lc = (LC);                                                          \
        int quad = lc & 3, l15 = (lc >> 2) & 15, t6 = lc >> 6;                  \
        int k = t6 % (K32C), nb = t6 / (K32C);                                  \
        p = (SRC) + (size_t)(nb * 16 + l15) * (KC) + k * 32 + quad * 8;         \
    }
    if (c < 1024)       SWZ(fc1w, c,          4, 128)
    else if (c < 2560)  SWZ(fc2w, c - 1024,   6, 192)
    else if (c < 2816)  SWZ(fc3w, c - 2560,   2, 64)
    else if (c < 11008) SWZ(ab1w, c - 2816,   8, 256)
    else                SWZ(ab2w, c - 11008,  8, 256)
#undef SWZ
    float4 v0 = *(const float4*)p;
    float4 v1 = *(const float4*)(p + 4);
    ushort4 o0, o1;
    o0.x = f2bf(v0.x); o0.y = f2bf(v0.y); o0.z = f2bf(v0.z); o0.w = f2bf(v0.w);
    o1.x = f2bf(v1.x); o1.y = f2bf(v1.y); o1.z = f2bf(v1.z); o1.w = f2bf(v1.w);
    *(ushort4*)(wc + (size_t)c * 8)     = o0;
    *(ushort4*)(wc + (size_t)c * 8 + 4) = o1;
}

// Wave-specialized, 768 threads = 12 waves: waves 0-3 = message branch
// (16 rows each), waves 4-11 = action branch (32-col N-chunk each ->
// acc[4][2] = 32 AGPRs, half of the 4-wave split). Static live-set ~80-84
// regs -> (768,6) gives 6 waves/EU = 2 blocks/CU = 24 waves (vs 14 at R11).
// B-fragment register dbuf + cross-barrier k=0 prefetch + cvt_pk retained.
__global__ __launch_bounds__(768, 6)
void actor_fused_kernel(const float* __restrict__ x, const float* __restrict__ m,
                        const float* __restrict__ fc1_b, const float* __restrict__ fc2_b,
                        const float* __restrict__ fc3_b,
                        const float* __restrict__ ab_b1, const float* __restrict__ ab_b2,
                        const float* __restrict__ ab_w3, const float* __restrict__ ab_b3,
                        const unsigned short* __restrict__ wc,
                        float* __restrict__ out, int Brows)
{
    __shared__ __align__(16) unsigned short smem[64 * ST];
    __shared__ float pw[8][64];

    const int t    = threadIdx.x;
    const int wave = t >> 6;
    const int lane = t & 63;
    const int l15  = lane & 15;
    const int quad = lane >> 4;
    const int loff = (l15 * 4 + quad) * 8;     // lane offset within 512-elem fragment block
    const int r0   = blockIdx.x * 64;
    const int aw2  = wave - 4;                 // action-wave index 0..7 (valid for wave>=4)

    // ---------------- stage: x -> bf16 + tanh(x); m -> tanh(m) ----------------
    // 2048 float4-slots per input over 768 threads: 3 iters, iter 2 is
    // wave-uniform-guarded (waves 8-11 skip). Load clause first.
    {
        const float* xp = x + (size_t)r0 * 128;
        const float* mp = m + (size_t)r0 * 128;
        float4 vv[3], gg[3];
        #pragma unroll
        for (int i = 0; i < 3; i++) {
            int slot = t + i * 768;
            if (slot < 2048) {
                vv[i] = *(const float4*)(xp + slot * 4);
                gg[i] = *(const float4*)(mp + slot * 4);
            }
        }
        #pragma unroll
        for (int i = 0; i < 3; i++) {
            int slot = t + i * 768;
            if (slot < 2048) {
                int idx = slot * 4;
                int row = idx >> 7, col = idx & 127;   // col % 4 == 0 -> 8B-aligned
                float4 v = vv[i];
                float4 g = gg[i];
                uint2 raw, tx, tm;
                raw.x = cvt_pk_bf16(v.x, v.y);
                raw.y = cvt_pk_bf16(v.z, v.w);
                tx.x  = cvt_pk_bf16(fast_tanh(v.x), fast_tanh(v.y));
                tx.y  = cvt_pk_bf16(fast_tanh(v.z), fast_tanh(v.w));
                tm.x  = cvt_pk_bf16(fast_tanh(g.x), fast_tanh(g.y));
                tm.y  = cvt_pk_bf16(fast_tanh(g.z), fast_tanh(g.w));
                *(uint2*)&smem[row * ST + col]       = raw;
                *(uint2*)&smem[row * ST + 128 + col] = tx;
                *(uint2*)&smem[row * ST + 256 + col] = tm;
            }
        }
    }

    // Prefetch k=0 B-fragments for the first post-S1 MFMA phase (fc1 / ab1).
    bf8_t pf[4];
    if (wave < 4) {
        #pragma unroll
        for (int nt = 0; nt < 4; nt++)
            pf[nt] = *(const bf8_t*)(wc + OFF_FC1 + (nt * 4 + 0) * 512 + loff);
    } else {
        #pragma unroll
        for (int nt = 0; nt < 2; nt++)
            pf[nt] = *(const bf8_t*)(wc + OFF_AB1 + ((aw2 * 2 + nt) * 8 + 0) * 512 + loff);
    }
    __syncthreads();   // S1: stage visible to all

    f4_t acc[4][2];    // action-branch ab1 accumulator; live across S2 (h1 write)
    bf8_t pf2[4];      // prefetch for post-S3 phase (msg fc3 uses 4; action ab2 k=0 uses 2)

    if (wave < 4) {
        // ================= MESSAGE BRANCH pre-S2: fc1 + fc2 =================
        const int mrow = wave * 16;

        // ---- fc1: hx = x @ fc1_w^T + b  (B double-buffered) ----
        f4_t hx[4] = {f4_t{0,0,0,0}, f4_t{0,0,0,0}, f4_t{0,0,0,0}, f4_t{0,0,0,0}};
        {
            bf8_t fb[2][4];
            #pragma unroll
            for (int nt = 0; nt < 4; nt++) fb[0][nt] = pf[nt];
            #pragma unroll
            for (int k = 0; k < 4; k++) {
                if (k < 3) {
                    #pragma unroll
                    for (int nt = 0; nt < 4; nt++)
                        fb[(k + 1) & 1][nt] = *(const bf8_t*)(wc + OFF_FC1 + (nt * 4 + k + 1) * 512 + loff);
                }
                bf8_t a = *(const bf8_t*)&smem[(mrow + l15) * ST + k * 32 + quad * 8];
                #pragma unroll
                for (int nt = 0; nt < 4; nt++)
                    hx[nt] = MFMA16(a, fb[k & 1][nt], hx[nt]);
            }
        }
        // fc2 k=0 prefetch: issues before the fc1 epilogue VALU, hides under it
        bf8_t fb2[2][4];
        #pragma unroll
        for (int nt = 0; nt < 4; nt++)
            fb2[0][nt] = *(const bf8_t*)(wc + OFF_FC2 + (nt * 6 + 0) * 512 + loff);
        {
            float bia[4], ss[4] = {0, 0, 0, 0};
            #pragma unroll
            for (int nt = 0; nt < 4; nt++) bia[nt] = fc1_b[nt * 16 + l15];
            #pragma unroll
            for (int nt = 0; nt < 4; nt++)
                #pragma unroll
                for (int r = 0; r < 4; r++) { hx[nt][r] += bia[nt]; ss[r] += hx[nt][r] * hx[nt][r]; }
            #pragma unroll
            for (int off = 1; off < 16; off <<= 1)
                #pragma unroll
                for (int r = 0; r < 4; r++) ss[r] += __shfl_xor(ss[r], off, 64);
            float inv[4];
            #pragma unroll
            for (int r = 0; r < 4; r++) inv[r] = rsqrtf(fmaxf(ss[r], 1e-24f));
            // z_hx = tanh(l2norm(hx)) -> cols [0:64)  (own 16-row band only)
            #pragma unroll
            for (int nt = 0; nt < 4; nt++) {
                unsigned int p01 = cvt_pk_bf16(fast_tanh(hx[nt][0] * inv[0]), fast_tanh(hx[nt][1] * inv[1]));
                unsigned int p23 = cvt_pk_bf16(fast_tanh(hx[nt][2] * inv[2]), fast_tanh(hx[nt][3] * inv[3]));
                smem[(mrow + quad * 4 + 0) * ST + nt * 16 + l15] = (unsigned short)p01;
                smem[(mrow + quad * 4 + 1) * ST + nt * 16 + l15] = (unsigned short)(p01 >> 16);
                smem[(mrow + quad * 4 + 2) * ST + nt * 16 + l15] = (unsigned short)p23;
                smem[(mrow + quad * 4 + 3) * ST + nt * 16 + l15] = (unsigned short)(p23 >> 16);
            }
        }
        // intra-wave LDS write->read ordering (own band only, no block barrier)
        asm volatile("s_waitcnt lgkmcnt(0)" ::: "memory");

        // ---- fc2: z2 = tanh([z_hx||tanh(m)] @ fc2_w^T + b)  K=192 (B dbuf) ----
        f4_t z2[4] = {f4_t{0,0,0,0}, f4_t{0,0,0,0}, f4_t{0,0,0,0}, f4_t{0,0,0,0}};
        #pragma unroll
        for (int k = 0; k < 6; k++) {
            if (k < 5) {
                #pragma unroll
                for (int nt = 0; nt < 4; nt++)
                    fb2[(k + 1) & 1][nt] = *(const bf8_t*)(wc + OFF_FC2 + (nt * 6 + k + 1) * 512 + loff);
            }
            int acol = (k < 2) ? (k * 32 + quad * 8) : (192 + k * 32 + quad * 8); // z_hx | tanh(m)
            bf8_t a = *(const bf8_t*)&smem[(mrow + l15) * ST + acol];
            #pragma unroll
            for (int nt = 0; nt < 4; nt++)
                z2[nt] = MFMA16(a, fb2[k & 1][nt], z2[nt]);
        }
        {
            float bia[4];
            #pragma unroll
            for (int nt = 0; nt < 4; nt++) bia[nt] = fc2_b[nt * 16 + l15];
            #pragma unroll
            for (int nt = 0; nt < 4; nt++) {
                unsigned int p01 = cvt_pk_bf16(fast_tanh(z2[nt][0] + bia[nt]), fast_tanh(z2[nt][1] + bia[nt]));
                unsigned int p23 = cvt_pk_bf16(fast_tanh(z2[nt][2] + bia[nt]), fast_tanh(z2[nt][3] + bia[nt]));
                smem[(mrow + quad * 4 + 0) * ST + 64 + nt * 16 + l15] = (unsigned short)p01;
                smem[(mrow + quad * 4 + 1) * ST + 64 + nt * 16 + l15] = (unsigned short)(p01 >> 16);
                smem[(mrow + quad * 4 + 2) * ST + 64 + nt * 16 + l15] = (unsigned short)p23;
                smem[(mrow + quad * 4 + 3) * ST + 64 + nt * 16 + l15] = (unsigned short)(p23 >> 16);
            }
        }
    } else {
        // ================= ACTION BRANCH pre-S2: ab1, 32 cols/wave (B dbuf) =================
        #pragma unroll
        for (int ms = 0; ms < 4; ms++)
            #pragma unroll
            for (int nt = 0; nt < 2; nt++) acc[ms][nt] = f4_t{0, 0, 0, 0};
        bf8_t ab[2][2];
        #pragma unroll
        for (int nt = 0; nt < 2; nt++) ab[0][nt] = pf[nt];
        #pragma unroll
        for (int k = 0; k < 8; k++) {
            if (k < 7) {
                #pragma unroll
                for (int nt = 0; nt < 2; nt++)
                    ab[(k + 1) & 1][nt] = *(const bf8_t*)(wc + OFF_AB1 + ((aw2 * 2 + nt) * 8 + k + 1) * 512 + loff);
            }
            bf8_t a[4];
            #pragma unroll
            for (int ms = 0; ms < 4; ms++)
                a[ms] = *(const bf8_t*)&smem[(ms * 16 + l15) * ST + 128 + k * 32 + quad * 8];
            #pragma unroll
            for (int nt = 0; nt < 2; nt++)
                #pragma unroll
                for (int ms = 0; ms < 4; ms++) acc[ms][nt] = MFMA16(a[ms], ab[k & 1][nt], acc[ms][nt]);
        }
    }
    __syncthreads();   // S2: all tanh-region reads (msg fc2 + ab1) complete

    if (wave >= 4) {
        // h1 = relu(ab1 + b1) -> overwrite tanh region (own 32-col band)
        float bia[2];
        #pragma unroll
        for (int nt = 0; nt < 2; nt++) bia[nt] = ab_b1[aw2 * 32 + nt * 16 + l15];
        #pragma unroll
        for (int ms = 0; ms < 4; ms++)
            #pragma unroll
            for (int nt = 0; nt < 2; nt++) {
                unsigned int p01 = cvt_pk_bf16(fmaxf(acc[ms][nt][0] + bia[nt], 0.0f),
                                               fmaxf(acc[ms][nt][1] + bia[nt], 0.0f));
                unsigned int p23 = cvt_pk_bf16(fmaxf(acc[ms][nt][2] + bia[nt], 0.0f),
                                               fmaxf(acc[ms][nt][3] + bia[nt], 0.0f));
                smem[(ms * 16 + quad * 4 + 0) * ST + 128 + aw2 * 32 + nt * 16 + l15] = (unsigned short)p01;
                smem[(ms * 16 + quad * 4 + 1) * ST + 128 + aw2 * 32 + nt * 16 + l15] = (unsigned short)(p01 >> 16);
                smem[(ms * 16 + quad * 4 + 2) * ST + 128 + aw2 * 32 + nt * 16 + l15] = (unsigned short)p23;
                smem[(ms * 16 + quad * 4 + 3) * ST + 128 + aw2 * 32 + nt * 16 + l15] = (unsigned short)(p23 >> 16);
            }
        // ab2 k=0 prefetch: in flight across S3
        #pragma unroll
        for (int nt = 0; nt < 2; nt++)
            pf2[nt] = *(const bf8_t*)(wc + OFF_AB2 + ((aw2 * 2 + nt) * 8 + 0) * 512 + loff);
    } else {
        // fc3 B-fragments (all 4): in flight across S3
        #pragma unroll
        for (int k = 0; k < 2; k++)
            #pragma unroll
            for (int nt = 0; nt < 2; nt++)
                pf2[k * 2 + nt] = *(const bf8_t*)(wc + OFF_FC3 + (nt * 2 + k) * 512 + loff);
    }
    __syncthreads();   // S3: h1 visible; msg fc3 overlaps ab2 below

    if (wave < 4) {
        // ---- fc3: msg = l2norm(z2 @ fc3_w^T + b)  K=64, N=32 (overlaps ab2) ----
        const int mrow = wave * 16;
        f4_t mg[2] = {f4_t{0,0,0,0}, f4_t{0,0,0,0}};
        #pragma unroll
        for (int k = 0; k < 2; k++) {
            bf8_t a = *(const bf8_t*)&smem[(mrow + l15) * ST + 64 + k * 32 + quad * 8];
            #pragma unroll
            for (int nt = 0; nt < 2; nt++)
                mg[nt] = MFMA16(a, pf2[k * 2 + nt], mg[nt]);
        }
        float bia[2], ss[4] = {0, 0, 0, 0};
        #pragma unroll
        for (int nt = 0; nt < 2; nt++) bia[nt] = fc3_b[nt * 16 + l15];
        #pragma unroll
        for (int nt = 0; nt < 2; nt++)
            #pragma unroll
            for (int r = 0; r < 4; r++) { mg[nt][r] += bia[nt]; ss[r] += mg[nt][r] * mg[nt][r]; }
        #pragma unroll
        for (int off = 1; off < 16; off <<= 1)
            #pragma unroll
            for (int r = 0; r < 4; r++) ss[r] += __shfl_xor(ss[r], off, 64);
        float inv[4];
        #pragma unroll
        for (int r = 0; r < 4; r++) inv[r] = rsqrtf(fmaxf(ss[r], 1e-24f));
        #pragma unroll
        for (int nt = 0; nt < 2; nt++)
            #pragma unroll
            for (int r = 0; r < 4; r++)
                out[(size_t)(r0 + mrow + quad * 4 + r) * 32 + nt * 16 + l15] = mg[nt][r] * inv[r];
    } else {
        // ---- ab2: h2 = relu(h1 @ w2^T + b2), fused ab3 dot, 32 cols/wave (B dbuf) ----
        #pragma unroll
        for (int ms = 0; ms < 4; ms++)
            #pragma unroll
            for (int nt = 0; nt < 2; nt++) acc[ms][nt] = f4_t{0, 0, 0, 0};
        bf8_t ab[2][2];
        #pragma unroll
        for (int nt = 0; nt < 2; nt++) ab[0][nt] = pf2[nt];
        #pragma unroll
        for (int k = 0; k < 8; k++) {
            if (k < 7) {
                #pragma unroll
                for (int nt = 0; nt < 2; nt++)
                    ab[(k + 1) & 1][nt] = *(const bf8_t*)(wc + OFF_AB2 + ((aw2 * 2 + nt) * 8 + k + 1) * 512 + loff);
            }
            bf8_t a[4];
            #pragma unroll
            for (int ms = 0; ms < 4; ms++)
                a[ms] = *(const bf8_t*)&smem[(ms * 16 + l15) * ST + 128 + k * 32 + quad * 8];
            #pragma unroll
            for (int nt = 0; nt < 2; nt++)
                #pragma unroll
                for (int ms = 0; ms < 4; ms++) acc[ms][nt] = MFMA16(a[ms], ab[k & 1][nt], acc[ms][nt]);
        }
        {
            float bia[2], w3v[2];
            #pragma unroll
            for (int nt = 0; nt < 2; nt++) {
                bia[nt] = ab_b2[aw2 * 32 + nt * 16 + l15];
                w3v[nt] = ab_w3[aw2 * 32 + nt * 16 + l15];
            }
            float p[4][4];
            #pragma unroll
            for (int ms = 0; ms < 4; ms++)
                #pragma unroll
                for (int r = 0; r < 4; r++) {
                    float s = 0.0f;
                    #pragma unroll
                    for (int nt = 0; nt < 2; nt++) s += fmaxf(acc[ms][nt][r] + bia[nt], 0.0f) * w3v[nt];
                    p[ms][r] = s;
                }
            #pragma unroll
            for (int off = 1; off < 16; off <<= 1)
                #pragma unroll
                for (int ms = 0; ms < 4; ms++)
                    #pragma unroll
                    for (int r = 0; r < 4; r++) p[ms][r] += __shfl_xor(p[ms][r], off, 64);
            if (l15 == 0) {
                #pragma unroll
                for (int ms = 0; ms < 4; ms++)
                    #pragma unroll
                    for (int r = 0; r < 4; r++) pw[aw2][ms * 16 + quad * 4 + r] = p[ms][r];
            }
        }
    }
    __syncthreads();   // S4: pw visible

    if (t < 64) {
        float a = pw[0][t] + pw[1][t] + pw[2][t] + pw[3][t]
                + pw[4][t] + pw[5][t] + pw[6][t] + pw[7][t] + ab_b3[0];
        out[(size_t)Brows * 32 + r0 + t] = fast_tanh(a);   // MAX_ACTION = 1
    }
}

extern "C" void kernel_launch(void* const* d_in, const int* in_sizes, int n_in,
                              void* d_out, int out_size, void* d_ws, size_t ws_size,
                              hipStream_t stream) {
    const float* x     = (const float*)d_in[0];
    const float* m     = (const float*)d_in[1];
    const float* fc1_w = (const float*)d_in[2];
    const float* fc1_b = (const float*)d_in[3];
    const float* fc2_w = (const float*)d_in[4];
    const float* fc2_b = (const float*)d_in[5];
    const float* fc3_w = (const float*)d_in[6];
    const float* fc3_b = (const float*)d_in[7];
    const float* ab_w1 = (const float*)d_in[8];
    const float* ab_b1 = (const float*)d_in[9];
    const float* ab_w2 = (const float*)d_in[10];
    const float* ab_b2 = (const float*)d_in[11];
    const float* ab_w3 = (const float*)d_in[12];
    const float* ab_b3 = (const float*)d_in[13];
    float* out = (float*)d_out;
    unsigned short* wc = (unsigned short*)d_ws;
    int Brows = in_sizes[0] / 128;   // 262144

    convert_weights_kernel<<<(W_CHUNKS + 255) / 256, 256, 0, stream>>>(fc1_w, fc2_w, fc3_w, ab_w1, ab_w2, wc);
    actor_fused_kernel<<<Brows / 64, 768, 0, stream>>>(x, m, fc1_b, fc2_b, fc3_b,
                                                       ab_b1, ab_b2, ab_w3, ab_b3, wc, out, Brows);
}